// Round 19
// baseline (208.261 us; speedup 1.0000x reference)
//
#include <hip/hip_runtime.h>

#define SEQ 2048
#define NTOK 4096
#define DM 1024
#define LDQK 3072

typedef __attribute__((ext_vector_type(4))) float f32x4;
typedef __attribute__((ext_vector_type(8))) short short8;
typedef __attribute__((ext_vector_type(4))) short short4v;

__device__ __forceinline__ short f2bf(float f) {
  union { float f; unsigned u; } x; x.f = f;
  unsigned r = x.u + 0x7fffu + ((x.u >> 16) & 1u);
  return (short)(r >> 16);
}

__device__ __forceinline__ float bf2f(short s) {
  union { unsigned u; float f; } x;
  x.u = ((unsigned)(unsigned short)s) << 16;
  return x.f;
}

__device__ __forceinline__ void async_load16(const void* g, void* l) {
  __builtin_amdgcn_global_load_lds(
      (const __attribute__((address_space(1))) void*)g,
      (__attribute__((address_space(3))) void*)l, 16, 0, 0);
}

// All prep in one launch. z=0..3: 1024x1024 W transposes; z=4: Wf1; z=5: Wf2;
// z=6: x f32->bf16 cast. Block (32,8).
__global__ void __launch_bounds__(256) prep_all(
    const float* __restrict__ Wq, const float* __restrict__ Wk,
    const float* __restrict__ Wv, const float* __restrict__ Wo,
    const float* __restrict__ Wf1, const float* __restrict__ Wf2,
    const float* __restrict__ x,
    short* __restrict__ Wqkv, short* __restrict__ Wto,
    short* __restrict__ Wtf1, short* __restrict__ Wtf2,
    short* __restrict__ xb) {
  const int z = blockIdx.z;
  const int tx = threadIdx.x, ty = threadIdx.y;
  if (z == 6) {
    int blk = blockIdx.y * 64 + blockIdx.x;
    int i = blk * 256 + ty * 32 + tx;
    f32x4 v = ((const f32x4*)x)[i];
    short4v o;
#pragma unroll
    for (int j = 0; j < 4; ++j) o[j] = f2bf(v[j]);
    ((short4v*)xb)[i] = o;
    return;
  }
  const float* in;
  short* out;
  int K, N;
  switch (z) {
    case 0: in = Wq;  out = Wqkv;               K = 1024; N = 1024; break;
    case 1: in = Wk;  out = Wqkv + 1024 * 1024; K = 1024; N = 1024; break;
    case 2: in = Wv;  out = Wqkv + 2048 * 1024; K = 1024; N = 1024; break;
    case 3: in = Wo;  out = Wto;                K = 1024; N = 1024; break;
    case 4: in = Wf1; out = Wtf1;               K = 1024; N = 2048; break;
    default: in = Wf2; out = Wtf2;              K = 2048; N = 1024; break;
  }
  if (blockIdx.x * 32 >= N || blockIdx.y * 32 >= K) return;
  __shared__ float t[32][33];
  const int n = blockIdx.x * 32 + tx;
#pragma unroll
  for (int i = 0; i < 4; ++i) {
    int k = blockIdx.y * 32 + ty + i * 8;
    t[ty + i * 8][tx] = in[(size_t)k * N + n];
  }
  __syncthreads();
  const int k2 = blockIdx.y * 32 + tx;
#pragma unroll
  for (int i = 0; i < 4; ++i) {
    int n2 = blockIdx.x * 32 + ty + i * 8;
    out[(size_t)n2 * K + k2] = f2bf(t[tx][ty + i * 8]);
  }
}

// QKV fused GEMM, 8 waves / 512 threads, block output 128x256.
// grid (12, 32). V region written directly transposed into Vt[B*H][64][SEQ].
__global__ void __launch_bounds__(512, 2) gemm_qkv8(
    const short* __restrict__ A, const short* __restrict__ Bt,
    const float* __restrict__ bq, const float* __restrict__ bk,
    const float* __restrict__ bv, short* __restrict__ Cout,
    short* __restrict__ VtOut) {
  __shared__ __align__(16) short As[128 * 64];   // 16KB
  __shared__ __align__(16) short Bs[256 * 64];   // 32KB
  const int tid = threadIdx.x;
  const int w = tid >> 6, lane = tid & 63;
  const int hi = lane >> 4, lo = lane & 15;
  const int bx = blockIdx.x, bm = blockIdx.y;
  const int wr = w >> 2, wc = w & 3;  // 2M x 4N wave grid; per-wave 64x64
  f32x4 acc[4][4] = {};

  for (int kt = 0; kt < 16; ++kt) {
#pragma unroll
    for (int i = 0; i < 2; ++i) {
      int c = i * 512 + tid;
      int r = c >> 3, scc = (c & 7) ^ (r & 7);
      async_load16(A + (size_t)(bm * 128 + r) * 1024 + kt * 64 + scc * 8,
                   &As[(i * 8 + w) * 512]);
    }
#pragma unroll
    for (int i = 0; i < 4; ++i) {
      int c = i * 512 + tid;
      int r = c >> 3, scc = (c & 7) ^ (r & 7);
      async_load16(Bt + (size_t)(bx * 256 + r) * 1024 + kt * 64 + scc * 8,
                   &Bs[(i * 8 + w) * 512]);
    }
    __syncthreads();
#pragma unroll
    for (int ks = 0; ks < 2; ++ks) {
      short8 af[4], bf[4];
#pragma unroll
      for (int m = 0; m < 4; ++m) {
        int row = wr * 64 + m * 16 + lo;
        int ch = (ks * 4 + hi) ^ (row & 7);
        af[m] = *(const short8*)(&As[row * 64 + ch * 8]);
      }
#pragma unroll
      for (int n = 0; n < 4; ++n) {
        int row = wc * 64 + n * 16 + lo;
        int ch = (ks * 4 + hi) ^ (row & 7);
        bf[n] = *(const short8*)(&Bs[row * 64 + ch * 8]);
      }
#pragma unroll
      for (int m = 0; m < 4; ++m)
#pragma unroll
        for (int n = 0; n < 4; ++n)
          acc[m][n] = __builtin_amdgcn_mfma_f32_16x16x32_bf16(af[m], bf[n], acc[m][n], 0, 0, 0);
    }
    __syncthreads();
  }
  const int colb = bx * 256 + wc * 64 + lo;
#pragma unroll
  for (int m = 0; m < 4; ++m) {
    int row0 = bm * 128 + wr * 64 + m * 16 + hi * 4;
#pragma unroll
    for (int n = 0; n < 4; ++n) {
      int col = colb + n * 16;
      int r3 = col >> 10;
      const float* bp = (r3 == 0) ? bq : ((r3 == 1) ? bk : bv);
      float bs = bp[col & 1023];
      if (r3 == 2) {
        // V region: write directly transposed into Vt[B*H][64][SEQ]
        int vdim = col - 2048;
        int hh = vdim >> 6, dd = vdim & 63;
        int bb = row0 >> 11, ss = row0 & 2047;
        short4v t;
#pragma unroll
        for (int j = 0; j < 4; ++j) t[j] = f2bf(acc[m][n][j] + bs);
        *(short4v*)&VtOut[((size_t)(bb * 16 + hh) * 64 + dd) * SEQ + ss] = t;
      } else {
#pragma unroll
        for (int j = 0; j < 4; ++j)
          Cout[(size_t)(row0 + j) * LDQK + col] = f2bf(acc[m][n][j] + bs);
      }
    }
  }
}

// C[M,N] = A[M,K](bf16) @ Bt[N,K](bf16)^T + bias.
// EPI: 0=bf16 out, 1=bf16 gelu. DBUF: double-buffered one-tile-ahead prefetch.
template <int EPI, bool DBUF>
__global__ void __launch_bounds__(256, 2) gemm_bt(
    const short* __restrict__ A, const short* __restrict__ Bt,
    const float* __restrict__ b0, void* __restrict__ Cout,
    int M, int N, int K) {
  __shared__ __align__(16) short As[DBUF ? 2 * 128 * 64 : 128 * 64];
  __shared__ __align__(16) short Bs[DBUF ? 2 * 128 * 64 : 128 * 64];
  const int w = threadIdx.x >> 6, lane = threadIdx.x & 63;
  const int hi = lane >> 4, lo = lane & 15;
  const int bm = blockIdx.y, bn = blockIdx.x;
  const int wr = w >> 1, wc = w & 1;
  f32x4 acc[4][4] = {};
  const int nkt = K >> 6;

  auto stage = [&](int kt, int buf) {
#pragma unroll
    for (int j = 0; j < 4; ++j) {
      int c = (j * 4 + w) * 64 + lane;
      int r = c >> 3;
      int scc = (c & 7) ^ (r & 7);
      async_load16(A + (size_t)(bm * 128 + r) * K + kt * 64 + scc * 8,
                   &As[buf * (128 * 64) + (j * 4 + w) * 512]);
      async_load16(Bt + (size_t)(bn * 128 + r) * K + kt * 64 + scc * 8,
                   &Bs[buf * (128 * 64) + (j * 4 + w) * 512]);
    }
  };

  if (DBUF) {
    stage(0, 0);
    __syncthreads();
  }

  for (int kt = 0; kt < nkt; ++kt) {
    int buf = 0;
    if (DBUF) {
      buf = kt & 1;
      if (kt + 1 < nkt) stage(kt + 1, buf ^ 1);
    } else {
      stage(kt, 0);
      __syncthreads();
    }
#pragma unroll
    for (int ks = 0; ks < 2; ++ks) {
      short8 af[4], bf[4];
#pragma unroll
      for (int m = 0; m < 4; ++m) {
        int row = wr * 64 + m * 16 + lo;
        int ch = (ks * 4 + hi) ^ (row & 7);
        af[m] = *(const short8*)(&As[buf * (128 * 64) + row * 64 + ch * 8]);
      }
#pragma unroll
      for (int n = 0; n < 4; ++n) {
        int row = wc * 64 + n * 16 + lo;
        int ch = (ks * 4 + hi) ^ (row & 7);
        bf[n] = *(const short8*)(&Bs[buf * (128 * 64) + row * 64 + ch * 8]);
      }
#pragma unroll
      for (int m = 0; m < 4; ++m)
#pragma unroll
        for (int n = 0; n < 4; ++n)
          acc[m][n] = __builtin_amdgcn_mfma_f32_16x16x32_bf16(af[m], bf[n], acc[m][n], 0, 0, 0);
    }
    __syncthreads();
  }
  const int colb = bn * 128 + wc * 64 + lo;
#pragma unroll
  for (int m = 0; m < 4; ++m) {
    int row0 = bm * 128 + wr * 64 + m * 16 + hi * 4;
#pragma unroll
    for (int n = 0; n < 4; ++n) {
      int col = colb + n * 16;
      float bs = b0[col];
#pragma unroll
      for (int j = 0; j < 4; ++j) {
        float v = acc[m][n][j] + bs;
        if (EPI == 1) v = 0.5f * v * (1.f + erff(v * 0.70710678f));
        ((short*)Cout)[(size_t)(row0 + j) * N + col] = f2bf(v);
      }
    }
  }
}

// 8-wave wide-block GEMM with dbuf prefetch: C = A @ Bt^T + bias (+resid).
// BM=128, BN=128, 512 threads as 2M x 4N waves, per-wave 64x32 (acc[4][2]).
// LDS 64KB, grid (N/128, M/128). Composes R16's wide-block (2x MFMA/barrier,
// halved A-restage) with the proven one-tile-ahead prefetch.
template <int EPI, bool RESID>
__global__ void __launch_bounds__(512, 2) gemm_w8d(
    const short* __restrict__ A, const short* __restrict__ Bt,
    const float* __restrict__ b0, const short* __restrict__ resid,
    short* __restrict__ Cout, int M, int N, int K) {
  __shared__ __align__(16) short As[2][128 * 64];
  __shared__ __align__(16) short Bs[2][128 * 64];
  const int tid = threadIdx.x;
  const int w = tid >> 6, lane = tid & 63;
  const int hi = lane >> 4, lo = lane & 15;
  const int bx = blockIdx.x, bm = blockIdx.y;
  const int wr = w >> 2, wc = w & 3;
  f32x4 acc[4][2] = {};
  const int nkt = K >> 6;

  auto stage = [&](int kt, int buf) {
#pragma unroll
    for (int i = 0; i < 2; ++i) {
      int c = i * 512 + tid;
      int r = c >> 3, scc = (c & 7) ^ (r & 7);
      async_load16(A + (size_t)(bm * 128 + r) * K + kt * 64 + scc * 8,
                   &As[buf][(i * 8 + w) * 512]);
    }
#pragma unroll
    for (int i = 0; i < 2; ++i) {
      int c = i * 512 + tid;
      int r = c >> 3, scc = (c & 7) ^ (r & 7);
      async_load16(Bt + (size_t)(bx * 128 + r) * K + kt * 64 + scc * 8,
                   &Bs[buf][(i * 8 + w) * 512]);
    }
  };

  stage(0, 0);
  __syncthreads();

  for (int kt = 0; kt < nkt; ++kt) {
    const int buf = kt & 1;
    if (kt + 1 < nkt) stage(kt + 1, buf ^ 1);  // prefetch next k-tile
#pragma unroll
    for (int ks = 0; ks < 2; ++ks) {
      short8 af[4], bf[2];
#pragma unroll
      for (int m = 0; m < 4; ++m) {
        int row = wr * 64 + m * 16 + lo;
        int ch = (ks * 4 + hi) ^ (row & 7);
        af[m] = *(const short8*)(&As[buf][row * 64 + ch * 8]);
      }
#pragma unroll
      for (int n = 0; n < 2; ++n) {
        int row = wc * 32 + n * 16 + lo;
        int ch = (ks * 4 + hi) ^ (row & 7);
        bf[n] = *(const short8*)(&Bs[buf][row * 64 + ch * 8]);
      }
#pragma unroll
      for (int m = 0; m < 4; ++m)
#pragma unroll
        for (int n = 0; n < 2; ++n)
          acc[m][n] = __builtin_amdgcn_mfma_f32_16x16x32_bf16(af[m], bf[n], acc[m][n], 0, 0, 0);
    }
    __syncthreads();  // readers done with buf; prefetch into buf^1 landed
  }
  const int colb = bx * 128 + wc * 32 + lo;
#pragma unroll
  for (int m = 0; m < 4; ++m) {
    int row0 = bm * 128 + wr * 64 + m * 16 + hi * 4;
#pragma unroll
    for (int n = 0; n < 2; ++n) {
      int col = colb + n * 16;
      float bs = b0[col];
#pragma unroll
      for (int j = 0; j < 4; ++j) {
        size_t idx = (size_t)(row0 + j) * N + col;
        float v = acc[m][n][j] + bs;
        if (EPI == 1) v = 0.5f * v * (1.f + erff(v * 0.70710678f));
        if (RESID) v += bf2f(resid[idx]);
        Cout[idx] = f2bf(v);
      }
    }
  }
}

// Flash attention. 64 q-rows/block (4 waves x 16 rows), KVBLK=64,
// dbuf K/V one-tile-ahead prefetch, 40KB LDS, grid 1024. No-max softmax,
// XOR-swizzled K/V reads, swapped QK^T, wave-private swizzled P,
// XCD-chunked swizzle, setprio around MFMA clusters.
__global__ void __launch_bounds__(256, 2) attn_kernel(
    const short* __restrict__ Qb, const short* __restrict__ Kb,
    const short* __restrict__ Vt, short* __restrict__ ctx) {
  const int w = threadIdx.x >> 6, lane = threadIdx.x & 63;
  const int hi = lane >> 4, lo = lane & 15;
  const int tid = threadIdx.x;
  const int L = blockIdx.x;
  const int W = (L & 7) * 128 + (L >> 3);
  const int qt = W & 31, bh = W >> 5;
  const int b = bh >> 4, h = bh & 15;
  const int qbase = qt * 64 + w * 16;
  const float C = 0.18033688f;  // 0.125 * log2(e)

  __shared__ __align__(16) short Ks[2][64 * 64];  // 16KB
  __shared__ __align__(16) short Vs[2][64 * 64];  // 16KB
  __shared__ __align__(16) short P[4][16 * 64];   // 8KB (wave-private)

  const short* qp = Qb + (size_t)(b * SEQ + qbase + lo) * LDQK + h * 64;
  short8 bq[2];
#pragma unroll
  for (int c = 0; c < 2; ++c)
    bq[c] = *(const short8*)(qp + c * 32 + hi * 8);

  const short* kb = Kb + (size_t)(b * SEQ) * LDQK + h * 64;
  const short* vb = Vt + (size_t)bh * 64 * SEQ;

  auto stage = [&](int kt, int buf) {
    const short* kg = kb + (size_t)(kt * 64) * LDQK;
#pragma unroll
    for (int i = 0; i < 2; ++i) {
      int c = i * 256 + tid;
      int r = c >> 3, scc = (c & 7) ^ (r & 7);
      async_load16(kg + (size_t)r * LDQK + scc * 8,
                   &Ks[buf][(i * 256 + w * 64) * 8]);
    }
    const short* vg = vb + kt * 64;
#pragma unroll
    for (int i = 0; i < 2; ++i) {
      int c = i * 256 + tid;
      int r = c >> 3, sc2 = (c & 7) ^ (r & 7);
      async_load16(vg + (size_t)r * SEQ + sc2 * 8,
                   &Vs[buf][(i * 256 + w * 64) * 8]);
    }
  };

  stage(0, 0);
  __syncthreads();

  f32x4 o[4] = {};
  float lacc = 0.f;
  const int x7 = lo & 7;

  for (int kt = 0; kt < SEQ / 64; ++kt) {
    const int buf = kt & 1;
    if (kt + 1 < SEQ / 64) stage(kt + 1, buf ^ 1);

    f32x4 s[4] = {};
    __builtin_amdgcn_s_setprio(1);
#pragma unroll
    for (int g = 0; g < 4; ++g) {
      const short* kr = &Ks[buf][(g * 16 + lo) * 64];
      short8 ka0 = *(const short8*)(kr + ((hi) ^ x7) * 8);
      short8 ka1 = *(const short8*)(kr + ((4 + hi) ^ x7) * 8);
      s[g] = __builtin_amdgcn_mfma_f32_16x16x32_bf16(ka0, bq[0], s[g], 0, 0, 0);
      s[g] = __builtin_amdgcn_mfma_f32_16x16x32_bf16(ka1, bq[1], s[g], 0, 0, 0);
    }
    __builtin_amdgcn_s_setprio(0);
    short8 vv[2][4];
#pragma unroll
    for (int ks = 0; ks < 2; ++ks)
#pragma unroll
      for (int a = 0; a < 4; ++a)
        vv[ks][a] = *(const short8*)(&Vs[buf][(a * 16 + lo) * 64 + (((ks * 4 + hi) ^ x7) * 8)]);

    float rsg[4];
    short* pbase = &P[w][0];
#pragma unroll
    for (int g = 0; g < 4; ++g) {
      float p0 = exp2f(s[g][0] * C);
      float p1 = exp2f(s[g][1] * C);
      float p2 = exp2f(s[g][2] * C);
      float p3 = exp2f(s[g][3] * C);
      rsg[g] = (p0 + p1) + (p2 + p3);
      unsigned w0, w1;
      asm("v_cvt_pk_bf16_f32 %0, %1, %2" : "=v"(w0) : "v"(p0), "v"(p1));
      asm("v_cvt_pk_bf16_f32 %0, %1, %2" : "=v"(w1) : "v"(p2), "v"(p3));
      union { unsigned uu[2]; short4v s4; } cv;
      cv.uu[0] = w0; cv.uu[1] = w1;
      int pc = (2 * g + (hi >> 1)) ^ x7;
      *(short4v*)(pbase + lo * 64 + pc * 8 + (hi & 1) * 4) = cv.s4;
    }
    __builtin_amdgcn_s_setprio(1);
#pragma unroll
    for (int ks = 0; ks < 2; ++ks) {
      int pc = (ks * 4 + hi) ^ x7;
      short8 pa = *(const short8*)(pbase + lo * 64 + pc * 8);
#pragma unroll
      for (int a = 0; a < 4; ++a)
        o[a] = __builtin_amdgcn_mfma_f32_16x16x32_bf16(pa, vv[ks][a], o[a], 0, 0, 0);
    }
    __builtin_amdgcn_s_setprio(0);
    lacc += (rsg[0] + rsg[1]) + (rsg[2] + rsg[3]);
    __syncthreads();
  }
  lacc += __shfl_xor(lacc, 16);
  lacc += __shfl_xor(lacc, 32);
#pragma unroll
  for (int j = 0; j < 4; ++j) {
    float lj = __shfl(lacc, hi * 4 + j);
    float inv = 1.f / lj;
    int row = qbase + hi * 4 + j;
#pragma unroll
    for (int a = 0; a < 4; ++a)
      ctx[(size_t)(b * SEQ + row) * DM + h * 64 + a * 16 + lo] = f2bf(o[a][j] * inv);
  }
}

// out = LN(in)*g + beta, in is bf16 (already residual-summed).
// Writes f32 outf and/or bf16 outb (nullable).
__global__ void __launch_bounds__(256) ln_bf16(
    const short* __restrict__ in, const float* __restrict__ g,
    const float* __restrict__ beta, float* __restrict__ outf,
    short* __restrict__ outb) {
  const int row = blockIdx.x;
  const int t = threadIdx.x;
  const size_t base = (size_t)row * DM;
  short4v iv = ((const short4v*)(in + base))[t];
  f32x4 v;
#pragma unroll
  for (int j = 0; j < 4; ++j) v[j] = bf2f(iv[j]);
  float s = v[0] + v[1] + v[2] + v[3];
  float s2 = v[0] * v[0] + v[1] * v[1] + v[2] * v[2] + v[3] * v[3];
#pragma unroll
  for (int off = 1; off < 64; off <<= 1) {
    s += __shfl_xor(s, off);
    s2 += __shfl_xor(s2, off);
  }
  __shared__ float rs[4], rs2[4];
  if ((t & 63) == 0) { rs[t >> 6] = s; rs2[t >> 6] = s2; }
  __syncthreads();
  s = rs[0] + rs[1] + rs[2] + rs[3];
  s2 = rs2[0] + rs2[1] + rs2[2] + rs2[3];
  float mu = s * (1.f / DM);
  float var = s2 * (1.f / DM) - mu * mu;
  float rstd = rsqrtf(var + 1e-5f);
  f32x4 gv = ((const f32x4*)g)[t];
  f32x4 bv = ((const f32x4*)beta)[t];
  f32x4 ov;
#pragma unroll
  for (int j = 0; j < 4; ++j) ov[j] = (v[j] - mu) * rstd * gv[j] + bv[j];
  if (outf) ((f32x4*)(outf + base))[t] = ov;
  if (outb) {
    short4v sb;
#pragma unroll
    for (int j = 0; j < 4; ++j) sb[j] = f2bf(ov[j]);
    ((short4v*)(outb + base))[t] = sb;
  }
}

extern "C" void kernel_launch(void* const* d_in, const int* in_sizes, int n_in,
                              void* d_out, int out_size, void* d_ws, size_t ws_size,
                              hipStream_t stream) {
  (void)in_sizes; (void)n_in; (void)out_size; (void)ws_size;
  const float* x   = (const float*)d_in[0];
  const float* Wq  = (const float*)d_in[1];
  const float* bq  = (const float*)d_in[2];
  const float* Wk  = (const float*)d_in[3];
  const float* bk  = (const float*)d_in[4];
  const float* Wv  = (const float*)d_in[5];
  const float* bv  = (const float*)d_in[6];
  const float* Wo  = (const float*)d_in[7];
  const float* bo  = (const float*)d_in[8];
  const float* g1  = (const float*)d_in[9];
  const float* b1  = (const float*)d_in[10];
  const float* Wf1 = (const float*)d_in[11];
  const float* bf1 = (const float*)d_in[12];
  const float* Wf2 = (const float*)d_in[13];
  const float* bf2 = (const float*)d_in[14];
  const float* g2  = (const float*)d_in[15];
  const float* b2  = (const float*)d_in[16];

  char* ws = (char*)d_ws;
  const size_t MB = 1u << 20;
  short* Wqkv = (short*)(ws + 0 * MB);    // [3072][1024] bf16, 6 MB
  short* Wto  = (short*)(ws + 6 * MB);    // 2 MB
  short* Wtf1 = (short*)(ws + 8 * MB);    // 4 MB
  short* Wtf2 = (short*)(ws + 12 * MB);   // 4 MB
  short* xb   = (short*)(ws + 16 * MB);   // 8 MB
  short* QKV  = (short*)(ws + 24 * MB);   // [4096][3072] bf16, 24 MB (V third unused)
  short* Vt   = (short*)(ws + 48 * MB);   // 8 MB (written by QKV gemm epilogue)
  short* ctxb = (short*)(ws + 56 * MB);   // 8 MB
  short* aout = (short*)(ws + 64 * MB);   // bf16 (x + ctx@Wo + bo), 8 MB
  short* x1b  = (short*)(ws + 72 * MB);   // bf16 LN1 output, 8 MB
  short* hb   = QKV;                       // QKV dead after attention
  short* ffo  = (short*)(ws + 48 * MB);   // bf16 (x1 + ffn), over Vt (dead)

  prep_all<<<dim3(64, 64, 7), dim3(32, 8), 0, stream>>>(
      Wq, Wk, Wv, Wo, Wf1, Wf2, x, Wqkv, Wto, Wtf1, Wtf2, xb);

  gemm_qkv8<<<dim3(12, 32), 512, 0, stream>>>(xb, Wqkv, bq, bk, bv, QKV, Vt);

  attn_kernel<<<dim3(1024), 256, 0, stream>>>(QKV, QKV + 1024, Vt, ctxb);

  // aout = x + ctx@Wo + bo (residual fused)
  gemm_w8d<0, true><<<dim3(8, 32), 512, 0, stream>>>(
      ctxb, Wto, bo, xb, aout, NTOK, 1024, 1024);
  ln_bf16<<<4096, 256, 0, stream>>>(aout, g1, b1, nullptr, x1b);
  gemm_bt<1, true><<<dim3(16, 32), 256, 0, stream>>>(
      x1b, Wtf1, bf1, hb, NTOK, 2048, 1024);
  // ffo = x1 + h@Wf2 + bf2 (residual fused)
  gemm_w8d<0, true><<<dim3(8, 32), 512, 0, stream>>>(
      hb, Wtf2, bf2, x1b, ffo, NTOK, 1024, 2048);
  ln_bf16<<<4096, 256, 0, stream>>>(ffo, g2, b2, (float*)d_out, nullptr);
}

// Round 20
// 206.854 us; speedup vs baseline: 1.0068x; 1.0068x over previous
//
#include <hip/hip_runtime.h>

#define SEQ 2048
#define NTOK 4096
#define DM 1024
#define LDQK 3072

typedef __attribute__((ext_vector_type(4))) float f32x4;
typedef __attribute__((ext_vector_type(8))) short short8;
typedef __attribute__((ext_vector_type(4))) short short4v;

__device__ __forceinline__ short f2bf(float f) {
  union { float f; unsigned u; } x; x.f = f;
  unsigned r = x.u + 0x7fffu + ((x.u >> 16) & 1u);
  return (short)(r >> 16);
}

__device__ __forceinline__ float bf2f(short s) {
  union { unsigned u; float f; } x;
  x.u = ((unsigned)(unsigned short)s) << 16;
  return x.f;
}

__device__ __forceinline__ void async_load16(const void* g, void* l) {
  __builtin_amdgcn_global_load_lds(
      (const __attribute__((address_space(1))) void*)g,
      (__attribute__((address_space(3))) void*)l, 16, 0, 0);
}

// All prep in one launch. z=0..3: 1024x1024 W transposes; z=4: Wf1; z=5: Wf2;
// z=6: x f32->bf16 cast. Block (32,8).
__global__ void __launch_bounds__(256) prep_all(
    const float* __restrict__ Wq, const float* __restrict__ Wk,
    const float* __restrict__ Wv, const float* __restrict__ Wo,
    const float* __restrict__ Wf1, const float* __restrict__ Wf2,
    const float* __restrict__ x,
    short* __restrict__ Wqkv, short* __restrict__ Wto,
    short* __restrict__ Wtf1, short* __restrict__ Wtf2,
    short* __restrict__ xb) {
  const int z = blockIdx.z;
  const int tx = threadIdx.x, ty = threadIdx.y;
  if (z == 6) {
    int blk = blockIdx.y * 64 + blockIdx.x;
    int i = blk * 256 + ty * 32 + tx;
    f32x4 v = ((const f32x4*)x)[i];
    short4v o;
#pragma unroll
    for (int j = 0; j < 4; ++j) o[j] = f2bf(v[j]);
    ((short4v*)xb)[i] = o;
    return;
  }
  const float* in;
  short* out;
  int K, N;
  switch (z) {
    case 0: in = Wq;  out = Wqkv;               K = 1024; N = 1024; break;
    case 1: in = Wk;  out = Wqkv + 1024 * 1024; K = 1024; N = 1024; break;
    case 2: in = Wv;  out = Wqkv + 2048 * 1024; K = 1024; N = 1024; break;
    case 3: in = Wo;  out = Wto;                K = 1024; N = 1024; break;
    case 4: in = Wf1; out = Wtf1;               K = 1024; N = 2048; break;
    default: in = Wf2; out = Wtf2;              K = 2048; N = 1024; break;
  }
  if (blockIdx.x * 32 >= N || blockIdx.y * 32 >= K) return;
  __shared__ float t[32][33];
  const int n = blockIdx.x * 32 + tx;
#pragma unroll
  for (int i = 0; i < 4; ++i) {
    int k = blockIdx.y * 32 + ty + i * 8;
    t[ty + i * 8][tx] = in[(size_t)k * N + n];
  }
  __syncthreads();
  const int k2 = blockIdx.y * 32 + tx;
#pragma unroll
  for (int i = 0; i < 4; ++i) {
    int n2 = blockIdx.x * 32 + ty + i * 8;
    out[(size_t)n2 * K + k2] = f2bf(t[tx][ty + i * 8]);
  }
}

// QKV fused GEMM, 8 waves / 512 threads, block output 128x256.
// grid (12, 32). V region written directly transposed into Vt[B*H][64][SEQ].
__global__ void __launch_bounds__(512, 2) gemm_qkv8(
    const short* __restrict__ A, const short* __restrict__ Bt,
    const float* __restrict__ bq, const float* __restrict__ bk,
    const float* __restrict__ bv, short* __restrict__ Cout,
    short* __restrict__ VtOut) {
  __shared__ __align__(16) short As[128 * 64];   // 16KB
  __shared__ __align__(16) short Bs[256 * 64];   // 32KB
  const int tid = threadIdx.x;
  const int w = tid >> 6, lane = tid & 63;
  const int hi = lane >> 4, lo = lane & 15;
  const int bx = blockIdx.x, bm = blockIdx.y;
  const int wr = w >> 2, wc = w & 3;  // 2M x 4N wave grid; per-wave 64x64
  f32x4 acc[4][4] = {};

  for (int kt = 0; kt < 16; ++kt) {
#pragma unroll
    for (int i = 0; i < 2; ++i) {
      int c = i * 512 + tid;
      int r = c >> 3, scc = (c & 7) ^ (r & 7);
      async_load16(A + (size_t)(bm * 128 + r) * 1024 + kt * 64 + scc * 8,
                   &As[(i * 8 + w) * 512]);
    }
#pragma unroll
    for (int i = 0; i < 4; ++i) {
      int c = i * 512 + tid;
      int r = c >> 3, scc = (c & 7) ^ (r & 7);
      async_load16(Bt + (size_t)(bx * 256 + r) * 1024 + kt * 64 + scc * 8,
                   &Bs[(i * 8 + w) * 512]);
    }
    __syncthreads();
#pragma unroll
    for (int ks = 0; ks < 2; ++ks) {
      short8 af[4], bf[4];
#pragma unroll
      for (int m = 0; m < 4; ++m) {
        int row = wr * 64 + m * 16 + lo;
        int ch = (ks * 4 + hi) ^ (row & 7);
        af[m] = *(const short8*)(&As[row * 64 + ch * 8]);
      }
#pragma unroll
      for (int n = 0; n < 4; ++n) {
        int row = wc * 64 + n * 16 + lo;
        int ch = (ks * 4 + hi) ^ (row & 7);
        bf[n] = *(const short8*)(&Bs[row * 64 + ch * 8]);
      }
#pragma unroll
      for (int m = 0; m < 4; ++m)
#pragma unroll
        for (int n = 0; n < 4; ++n)
          acc[m][n] = __builtin_amdgcn_mfma_f32_16x16x32_bf16(af[m], bf[n], acc[m][n], 0, 0, 0);
    }
    __syncthreads();
  }
  const int colb = bx * 256 + wc * 64 + lo;
#pragma unroll
  for (int m = 0; m < 4; ++m) {
    int row0 = bm * 128 + wr * 64 + m * 16 + hi * 4;
#pragma unroll
    for (int n = 0; n < 4; ++n) {
      int col = colb + n * 16;
      int r3 = col >> 10;
      const float* bp = (r3 == 0) ? bq : ((r3 == 1) ? bk : bv);
      float bs = bp[col & 1023];
      if (r3 == 2) {
        // V region: write directly transposed into Vt[B*H][64][SEQ]
        int vdim = col - 2048;
        int hh = vdim >> 6, dd = vdim & 63;
        int bb = row0 >> 11, ss = row0 & 2047;
        short4v t;
#pragma unroll
        for (int j = 0; j < 4; ++j) t[j] = f2bf(acc[m][n][j] + bs);
        *(short4v*)&VtOut[((size_t)(bb * 16 + hh) * 64 + dd) * SEQ + ss] = t;
      } else {
#pragma unroll
        for (int j = 0; j < 4; ++j)
          Cout[(size_t)(row0 + j) * LDQK + col] = f2bf(acc[m][n][j] + bs);
      }
    }
  }
}

// C[M,N] = A[M,K] @ Bt[N,K]^T + bias + resid(bf16), bf16 out. 128x64 tile,
// 4 waves, double-buffered prefetch (R16-proven for O-proj/FF2).
__global__ void __launch_bounds__(256, 2) gemm_n64(
    const short* __restrict__ A, const short* __restrict__ Bt,
    const float* __restrict__ b0, const short* __restrict__ resid,
    short* __restrict__ Cout, int M, int N, int K) {
  __shared__ __align__(16) short As[2][128 * 64];
  __shared__ __align__(16) short Bs[2][64 * 64];
  const int w = threadIdx.x >> 6, lane = threadIdx.x & 63;
  const int hi = lane >> 4, lo = lane & 15;
  const int bm = blockIdx.y, bn = blockIdx.x;
  const int wr = w >> 1, wc = w & 1;
  f32x4 acc[4][2] = {};
  const int nkt = K >> 6;

  auto stage = [&](int kt, int buf) {
#pragma unroll
    for (int j = 0; j < 4; ++j) {
      int c = (j * 4 + w) * 64 + lane;
      int r = c >> 3;
      int scc = (c & 7) ^ (r & 7);
      async_load16(A + (size_t)(bm * 128 + r) * K + kt * 64 + scc * 8,
                   &As[buf][(j * 4 + w) * 512]);
    }
#pragma unroll
    for (int j = 0; j < 2; ++j) {
      int c = j * 256 + w * 64 + lane;
      int r = c >> 3;
      int scc = (c & 7) ^ (r & 7);
      async_load16(Bt + (size_t)(bn * 64 + r) * K + kt * 64 + scc * 8,
                   &Bs[buf][(j * 256 + w * 64) * 8]);
    }
  };

  stage(0, 0);
  __syncthreads();

  for (int kt = 0; kt < nkt; ++kt) {
    const int buf = kt & 1;
    if (kt + 1 < nkt) stage(kt + 1, buf ^ 1);
#pragma unroll
    for (int ks = 0; ks < 2; ++ks) {
      short8 af[4], bf[2];
#pragma unroll
      for (int m = 0; m < 4; ++m) {
        int row = wr * 64 + m * 16 + lo;
        int ch = (ks * 4 + hi) ^ (row & 7);
        af[m] = *(const short8*)(&As[buf][row * 64 + ch * 8]);
      }
#pragma unroll
      for (int n = 0; n < 2; ++n) {
        int row = wc * 32 + n * 16 + lo;
        int ch = (ks * 4 + hi) ^ (row & 7);
        bf[n] = *(const short8*)(&Bs[buf][row * 64 + ch * 8]);
      }
#pragma unroll
      for (int m = 0; m < 4; ++m)
#pragma unroll
        for (int n = 0; n < 2; ++n)
          acc[m][n] = __builtin_amdgcn_mfma_f32_16x16x32_bf16(af[m], bf[n], acc[m][n], 0, 0, 0);
    }
    __syncthreads();
  }
  const int colb = bn * 64 + wc * 32 + lo;
#pragma unroll
  for (int m = 0; m < 4; ++m) {
    int row0 = bm * 128 + wr * 64 + m * 16 + hi * 4;
#pragma unroll
    for (int n = 0; n < 2; ++n) {
      int col = colb + n * 16;
      float bs = b0[col];
#pragma unroll
      for (int j = 0; j < 4; ++j) {
        size_t idx = (size_t)(row0 + j) * N + col;
        Cout[idx] = f2bf(acc[m][n][j] + bs + bf2f(resid[idx]));
      }
    }
  }
}

// 8-wave wide-block GEMM with dbuf prefetch (for FF1: grid 512 = 2 blocks/CU
// -> 16 waves/CU, 2x the 4-wave version, + halved A-restage traffic).
// BM=128, BN=128, per-wave 64x32 (acc[4][2]). LDS 64KB.
template <int EPI, bool RESID>
__global__ void __launch_bounds__(512, 2) gemm_w8d(
    const short* __restrict__ A, const short* __restrict__ Bt,
    const float* __restrict__ b0, const short* __restrict__ resid,
    short* __restrict__ Cout, int M, int N, int K) {
  __shared__ __align__(16) short As[2][128 * 64];
  __shared__ __align__(16) short Bs[2][128 * 64];
  const int tid = threadIdx.x;
  const int w = tid >> 6, lane = tid & 63;
  const int hi = lane >> 4, lo = lane & 15;
  const int bx = blockIdx.x, bm = blockIdx.y;
  const int wr = w >> 2, wc = w & 3;
  f32x4 acc[4][2] = {};
  const int nkt = K >> 6;

  auto stage = [&](int kt, int buf) {
#pragma unroll
    for (int i = 0; i < 2; ++i) {
      int c = i * 512 + tid;
      int r = c >> 3, scc = (c & 7) ^ (r & 7);
      async_load16(A + (size_t)(bm * 128 + r) * K + kt * 64 + scc * 8,
                   &As[buf][(i * 8 + w) * 512]);
    }
#pragma unroll
    for (int i = 0; i < 2; ++i) {
      int c = i * 512 + tid;
      int r = c >> 3, scc = (c & 7) ^ (r & 7);
      async_load16(Bt + (size_t)(bx * 128 + r) * K + kt * 64 + scc * 8,
                   &Bs[buf][(i * 8 + w) * 512]);
    }
  };

  stage(0, 0);
  __syncthreads();

  for (int kt = 0; kt < nkt; ++kt) {
    const int buf = kt & 1;
    if (kt + 1 < nkt) stage(kt + 1, buf ^ 1);  // prefetch next k-tile
#pragma unroll
    for (int ks = 0; ks < 2; ++ks) {
      short8 af[4], bf[2];
#pragma unroll
      for (int m = 0; m < 4; ++m) {
        int row = wr * 64 + m * 16 + lo;
        int ch = (ks * 4 + hi) ^ (row & 7);
        af[m] = *(const short8*)(&As[buf][row * 64 + ch * 8]);
      }
#pragma unroll
      for (int n = 0; n < 2; ++n) {
        int row = wc * 32 + n * 16 + lo;
        int ch = (ks * 4 + hi) ^ (row & 7);
        bf[n] = *(const short8*)(&Bs[buf][row * 64 + ch * 8]);
      }
#pragma unroll
      for (int m = 0; m < 4; ++m)
#pragma unroll
        for (int n = 0; n < 2; ++n)
          acc[m][n] = __builtin_amdgcn_mfma_f32_16x16x32_bf16(af[m], bf[n], acc[m][n], 0, 0, 0);
    }
    __syncthreads();  // readers done with buf; prefetch into buf^1 landed
  }
  const int colb = bx * 128 + wc * 32 + lo;
#pragma unroll
  for (int m = 0; m < 4; ++m) {
    int row0 = bm * 128 + wr * 64 + m * 16 + hi * 4;
#pragma unroll
    for (int n = 0; n < 2; ++n) {
      int col = colb + n * 16;
      float bs = b0[col];
#pragma unroll
      for (int j = 0; j < 4; ++j) {
        size_t idx = (size_t)(row0 + j) * N + col;
        float v = acc[m][n][j] + bs;
        if (EPI == 1) v = 0.5f * v * (1.f + erff(v * 0.70710678f));
        if (RESID) v += bf2f(resid[idx]);
        Cout[idx] = f2bf(v);
      }
    }
  }
}

// Flash attention. 64 q-rows/block (4 waves x 16 rows), KVBLK=64,
// dbuf K/V one-tile-ahead prefetch, 40KB LDS, grid 1024. No-max softmax,
// XOR-swizzled K/V reads, swapped QK^T, wave-private swizzled P,
// XCD-chunked swizzle, setprio around MFMA clusters.
__global__ void __launch_bounds__(256, 2) attn_kernel(
    const short* __restrict__ Qb, const short* __restrict__ Kb,
    const short* __restrict__ Vt, short* __restrict__ ctx) {
  const int w = threadIdx.x >> 6, lane = threadIdx.x & 63;
  const int hi = lane >> 4, lo = lane & 15;
  const int tid = threadIdx.x;
  const int L = blockIdx.x;
  const int W = (L & 7) * 128 + (L >> 3);
  const int qt = W & 31, bh = W >> 5;
  const int b = bh >> 4, h = bh & 15;
  const int qbase = qt * 64 + w * 16;
  const float C = 0.18033688f;  // 0.125 * log2(e)

  __shared__ __align__(16) short Ks[2][64 * 64];  // 16KB
  __shared__ __align__(16) short Vs[2][64 * 64];  // 16KB
  __shared__ __align__(16) short P[4][16 * 64];   // 8KB (wave-private)

  const short* qp = Qb + (size_t)(b * SEQ + qbase + lo) * LDQK + h * 64;
  short8 bq[2];
#pragma unroll
  for (int c = 0; c < 2; ++c)
    bq[c] = *(const short8*)(qp + c * 32 + hi * 8);

  const short* kb = Kb + (size_t)(b * SEQ) * LDQK + h * 64;
  const short* vb = Vt + (size_t)bh * 64 * SEQ;

  auto stage = [&](int kt, int buf) {
    const short* kg = kb + (size_t)(kt * 64) * LDQK;
#pragma unroll
    for (int i = 0; i < 2; ++i) {
      int c = i * 256 + tid;
      int r = c >> 3, scc = (c & 7) ^ (r & 7);
      async_load16(kg + (size_t)r * LDQK + scc * 8,
                   &Ks[buf][(i * 256 + w * 64) * 8]);
    }
    const short* vg = vb + kt * 64;
#pragma unroll
    for (int i = 0; i < 2; ++i) {
      int c = i * 256 + tid;
      int r = c >> 3, sc2 = (c & 7) ^ (r & 7);
      async_load16(vg + (size_t)r * SEQ + sc2 * 8,
                   &Vs[buf][(i * 256 + w * 64) * 8]);
    }
  };

  stage(0, 0);
  __syncthreads();

  f32x4 o[4] = {};
  float lacc = 0.f;
  const int x7 = lo & 7;

  for (int kt = 0; kt < SEQ / 64; ++kt) {
    const int buf = kt & 1;
    if (kt + 1 < SEQ / 64) stage(kt + 1, buf ^ 1);

    f32x4 s[4] = {};
    __builtin_amdgcn_s_setprio(1);
#pragma unroll
    for (int g = 0; g < 4; ++g) {
      const short* kr = &Ks[buf][(g * 16 + lo) * 64];
      short8 ka0 = *(const short8*)(kr + ((hi) ^ x7) * 8);
      short8 ka1 = *(const short8*)(kr + ((4 + hi) ^ x7) * 8);
      s[g] = __builtin_amdgcn_mfma_f32_16x16x32_bf16(ka0, bq[0], s[g], 0, 0, 0);
      s[g] = __builtin_amdgcn_mfma_f32_16x16x32_bf16(ka1, bq[1], s[g], 0, 0, 0);
    }
    __builtin_amdgcn_s_setprio(0);
    short8 vv[2][4];
#pragma unroll
    for (int ks = 0; ks < 2; ++ks)
#pragma unroll
      for (int a = 0; a < 4; ++a)
        vv[ks][a] = *(const short8*)(&Vs[buf][(a * 16 + lo) * 64 + (((ks * 4 + hi) ^ x7) * 8)]);

    float rsg[4];
    short* pbase = &P[w][0];
#pragma unroll
    for (int g = 0; g < 4; ++g) {
      float p0 = exp2f(s[g][0] * C);
      float p1 = exp2f(s[g][1] * C);
      float p2 = exp2f(s[g][2] * C);
      float p3 = exp2f(s[g][3] * C);
      rsg[g] = (p0 + p1) + (p2 + p3);
      unsigned w0, w1;
      asm("v_cvt_pk_bf16_f32 %0, %1, %2" : "=v"(w0) : "v"(p0), "v"(p1));
      asm("v_cvt_pk_bf16_f32 %0, %1, %2" : "=v"(w1) : "v"(p2), "v"(p3));
      union { unsigned uu[2]; short4v s4; } cv;
      cv.uu[0] = w0; cv.uu[1] = w1;
      int pc = (2 * g + (hi >> 1)) ^ x7;
      *(short4v*)(pbase + lo * 64 + pc * 8 + (hi & 1) * 4) = cv.s4;
    }
    __builtin_amdgcn_s_setprio(1);
#pragma unroll
    for (int ks = 0; ks < 2; ++ks) {
      int pc = (ks * 4 + hi) ^ x7;
      short8 pa = *(const short8*)(pbase + lo * 64 + pc * 8);
#pragma unroll
      for (int a = 0; a < 4; ++a)
        o[a] = __builtin_amdgcn_mfma_f32_16x16x32_bf16(pa, vv[ks][a], o[a], 0, 0, 0);
    }
    __builtin_amdgcn_s_setprio(0);
    lacc += (rsg[0] + rsg[1]) + (rsg[2] + rsg[3]);
    __syncthreads();
  }
  lacc += __shfl_xor(lacc, 16);
  lacc += __shfl_xor(lacc, 32);
#pragma unroll
  for (int j = 0; j < 4; ++j) {
    float lj = __shfl(lacc, hi * 4 + j);
    float inv = 1.f / lj;
    int row = qbase + hi * 4 + j;
#pragma unroll
    for (int a = 0; a < 4; ++a)
      ctx[(size_t)(b * SEQ + row) * DM + h * 64 + a * 16 + lo] = f2bf(o[a][j] * inv);
  }
}

// out = LN(in)*g + beta, in is bf16 (already residual-summed).
// Writes f32 outf and/or bf16 outb (nullable).
__global__ void __launch_bounds__(256) ln_bf16(
    const short* __restrict__ in, const float* __restrict__ g,
    const float* __restrict__ beta, float* __restrict__ outf,
    short* __restrict__ outb) {
  const int row = blockIdx.x;
  const int t = threadIdx.x;
  const size_t base = (size_t)row * DM;
  short4v iv = ((const short4v*)(in + base))[t];
  f32x4 v;
#pragma unroll
  for (int j = 0; j < 4; ++j) v[j] = bf2f(iv[j]);
  float s = v[0] + v[1] + v[2] + v[3];
  float s2 = v[0] * v[0] + v[1] * v[1] + v[2] * v[2] + v[3] * v[3];
#pragma unroll
  for (int off = 1; off < 64; off <<= 1) {
    s += __shfl_xor(s, off);
    s2 += __shfl_xor(s2, off);
  }
  __shared__ float rs[4], rs2[4];
  if ((t & 63) == 0) { rs[t >> 6] = s; rs2[t >> 6] = s2; }
  __syncthreads();
  s = rs[0] + rs[1] + rs[2] + rs[3];
  s2 = rs2[0] + rs2[1] + rs2[2] + rs2[3];
  float mu = s * (1.f / DM);
  float var = s2 * (1.f / DM) - mu * mu;
  float rstd = rsqrtf(var + 1e-5f);
  f32x4 gv = ((const f32x4*)g)[t];
  f32x4 bv = ((const f32x4*)beta)[t];
  f32x4 ov;
#pragma unroll
  for (int j = 0; j < 4; ++j) ov[j] = (v[j] - mu) * rstd * gv[j] + bv[j];
  if (outf) ((f32x4*)(outf + base))[t] = ov;
  if (outb) {
    short4v sb;
#pragma unroll
    for (int j = 0; j < 4; ++j) sb[j] = f2bf(ov[j]);
    ((short4v*)(outb + base))[t] = sb;
  }
}

extern "C" void kernel_launch(void* const* d_in, const int* in_sizes, int n_in,
                              void* d_out, int out_size, void* d_ws, size_t ws_size,
                              hipStream_t stream) {
  (void)in_sizes; (void)n_in; (void)out_size; (void)ws_size;
  const float* x   = (const float*)d_in[0];
  const float* Wq  = (const float*)d_in[1];
  const float* bq  = (const float*)d_in[2];
  const float* Wk  = (const float*)d_in[3];
  const float* bk  = (const float*)d_in[4];
  const float* Wv  = (const float*)d_in[5];
  const float* bv  = (const float*)d_in[6];
  const float* Wo  = (const float*)d_in[7];
  const float* bo  = (const float*)d_in[8];
  const float* g1  = (const float*)d_in[9];
  const float* b1  = (const float*)d_in[10];
  const float* Wf1 = (const float*)d_in[11];
  const float* bf1 = (const float*)d_in[12];
  const float* Wf2 = (const float*)d_in[13];
  const float* bf2 = (const float*)d_in[14];
  const float* g2  = (const float*)d_in[15];
  const float* b2  = (const float*)d_in[16];

  char* ws = (char*)d_ws;
  const size_t MB = 1u << 20;
  short* Wqkv = (short*)(ws + 0 * MB);    // [3072][1024] bf16, 6 MB
  short* Wto  = (short*)(ws + 6 * MB);    // 2 MB
  short* Wtf1 = (short*)(ws + 8 * MB);    // 4 MB
  short* Wtf2 = (short*)(ws + 12 * MB);   // 4 MB
  short* xb   = (short*)(ws + 16 * MB);   // 8 MB
  short* QKV  = (short*)(ws + 24 * MB);   // [4096][3072] bf16, 24 MB (V third unused)
  short* Vt   = (short*)(ws + 48 * MB);   // 8 MB (written by QKV gemm epilogue)
  short* ctxb = (short*)(ws + 56 * MB);   // 8 MB
  short* aout = (short*)(ws + 64 * MB);   // bf16 (x + ctx@Wo + bo), 8 MB
  short* x1b  = (short*)(ws + 72 * MB);   // bf16 LN1 output, 8 MB
  short* hb   = QKV;                       // QKV dead after attention
  short* ffo  = (short*)(ws + 48 * MB);   // bf16 (x1 + ffn), over Vt (dead)

  prep_all<<<dim3(64, 64, 7), dim3(32, 8), 0, stream>>>(
      Wq, Wk, Wv, Wo, Wf1, Wf2, x, Wqkv, Wto, Wtf1, Wtf2, xb);

  gemm_qkv8<<<dim3(12, 32), 512, 0, stream>>>(xb, Wqkv, bq, bk, bv, QKV, Vt);

  attn_kernel<<<dim3(1024), 256, 0, stream>>>(QKV, QKV + 1024, Vt, ctxb);

  // aout = x + ctx@Wo + bo (residual fused)
  gemm_n64<<<dim3(16, 32), 256, 0, stream>>>(ctxb, Wto, bo, xb, aout, NTOK, 1024, 1024);
  ln_bf16<<<4096, 256, 0, stream>>>(aout, g1, b1, nullptr, x1b);
  // FF1: 8-wave wide-block dbuf (grid 512 = 2 blocks/CU -> 16 waves/CU)
  gemm_w8d<1, false><<<dim3(16, 32), 512, 0, stream>>>(
      x1b, Wtf1, bf1, nullptr, hb, NTOK, 2048, 1024);
  // ffo = x1 + h@Wf2 + bf2 (residual fused)
  gemm_n64<<<dim3(16, 32), 256, 0, stream>>>(hb, Wtf2, bf2, x1b, ffo, NTOK, 1024, 2048);
  ln_bf16<<<4096, 256, 0, stream>>>(ffo, g2, b2, (float*)d_out, nullptr);
}

// Round 21
// 203.629 us; speedup vs baseline: 1.0227x; 1.0158x over previous
//
#include <hip/hip_runtime.h>

#define SEQ 2048
#define NTOK 4096
#define DM 1024
#define LDQK 3072

typedef __attribute__((ext_vector_type(4))) float f32x4;
typedef __attribute__((ext_vector_type(8))) short short8;
typedef __attribute__((ext_vector_type(4))) short short4v;

__device__ __forceinline__ short f2bf(float f) {
  union { float f; unsigned u; } x; x.f = f;
  unsigned r = x.u + 0x7fffu + ((x.u >> 16) & 1u);
  return (short)(r >> 16);
}

__device__ __forceinline__ float bf2f(short s) {
  union { unsigned u; float f; } x;
  x.u = ((unsigned)(unsigned short)s) << 16;
  return x.f;
}

__device__ __forceinline__ void async_load16(const void* g, void* l) {
  __builtin_amdgcn_global_load_lds(
      (const __attribute__((address_space(1))) void*)g,
      (__attribute__((address_space(3))) void*)l, 16, 0, 0);
}

// All prep in one launch. z=0..3: 1024x1024 W transposes; z=4: Wf1; z=5: Wf2;
// z=6: x f32->bf16 cast. Block (32,8).
__global__ void __launch_bounds__(256) prep_all(
    const float* __restrict__ Wq, const float* __restrict__ Wk,
    const float* __restrict__ Wv, const float* __restrict__ Wo,
    const float* __restrict__ Wf1, const float* __restrict__ Wf2,
    const float* __restrict__ x,
    short* __restrict__ Wqkv, short* __restrict__ Wto,
    short* __restrict__ Wtf1, short* __restrict__ Wtf2,
    short* __restrict__ xb) {
  const int z = blockIdx.z;
  const int tx = threadIdx.x, ty = threadIdx.y;
  if (z == 6) {
    int blk = blockIdx.y * 64 + blockIdx.x;
    int i = blk * 256 + ty * 32 + tx;
    f32x4 v = ((const f32x4*)x)[i];
    short4v o;
#pragma unroll
    for (int j = 0; j < 4; ++j) o[j] = f2bf(v[j]);
    ((short4v*)xb)[i] = o;
    return;
  }
  const float* in;
  short* out;
  int K, N;
  switch (z) {
    case 0: in = Wq;  out = Wqkv;               K = 1024; N = 1024; break;
    case 1: in = Wk;  out = Wqkv + 1024 * 1024; K = 1024; N = 1024; break;
    case 2: in = Wv;  out = Wqkv + 2048 * 1024; K = 1024; N = 1024; break;
    case 3: in = Wo;  out = Wto;                K = 1024; N = 1024; break;
    case 4: in = Wf1; out = Wtf1;               K = 1024; N = 2048; break;
    default: in = Wf2; out = Wtf2;              K = 2048; N = 1024; break;
  }
  if (blockIdx.x * 32 >= N || blockIdx.y * 32 >= K) return;
  __shared__ float t[32][33];
  const int n = blockIdx.x * 32 + tx;
#pragma unroll
  for (int i = 0; i < 4; ++i) {
    int k = blockIdx.y * 32 + ty + i * 8;
    t[ty + i * 8][tx] = in[(size_t)k * N + n];
  }
  __syncthreads();
  const int k2 = blockIdx.y * 32 + tx;
#pragma unroll
  for (int i = 0; i < 4; ++i) {
    int n2 = blockIdx.x * 32 + ty + i * 8;
    out[(size_t)n2 * K + k2] = f2bf(t[tx][ty + i * 8]);
  }
}

// QKV fused GEMM, 8 waves / 512 threads, block output 128x256.
// grid (12, 32). V region written directly transposed into Vt[B*H][64][SEQ].
__global__ void __launch_bounds__(512, 2) gemm_qkv8(
    const short* __restrict__ A, const short* __restrict__ Bt,
    const float* __restrict__ bq, const float* __restrict__ bk,
    const float* __restrict__ bv, short* __restrict__ Cout,
    short* __restrict__ VtOut) {
  __shared__ __align__(16) short As[128 * 64];   // 16KB
  __shared__ __align__(16) short Bs[256 * 64];   // 32KB
  const int tid = threadIdx.x;
  const int w = tid >> 6, lane = tid & 63;
  const int hi = lane >> 4, lo = lane & 15;
  const int bx = blockIdx.x, bm = blockIdx.y;
  const int wr = w >> 2, wc = w & 3;  // 2M x 4N wave grid; per-wave 64x64
  f32x4 acc[4][4] = {};

  for (int kt = 0; kt < 16; ++kt) {
#pragma unroll
    for (int i = 0; i < 2; ++i) {
      int c = i * 512 + tid;
      int r = c >> 3, scc = (c & 7) ^ (r & 7);
      async_load16(A + (size_t)(bm * 128 + r) * 1024 + kt * 64 + scc * 8,
                   &As[(i * 8 + w) * 512]);
    }
#pragma unroll
    for (int i = 0; i < 4; ++i) {
      int c = i * 512 + tid;
      int r = c >> 3, scc = (c & 7) ^ (r & 7);
      async_load16(Bt + (size_t)(bx * 256 + r) * 1024 + kt * 64 + scc * 8,
                   &Bs[(i * 8 + w) * 512]);
    }
    __syncthreads();
#pragma unroll
    for (int ks = 0; ks < 2; ++ks) {
      short8 af[4], bf[4];
#pragma unroll
      for (int m = 0; m < 4; ++m) {
        int row = wr * 64 + m * 16 + lo;
        int ch = (ks * 4 + hi) ^ (row & 7);
        af[m] = *(const short8*)(&As[row * 64 + ch * 8]);
      }
#pragma unroll
      for (int n = 0; n < 4; ++n) {
        int row = wc * 64 + n * 16 + lo;
        int ch = (ks * 4 + hi) ^ (row & 7);
        bf[n] = *(const short8*)(&Bs[row * 64 + ch * 8]);
      }
#pragma unroll
      for (int m = 0; m < 4; ++m)
#pragma unroll
        for (int n = 0; n < 4; ++n)
          acc[m][n] = __builtin_amdgcn_mfma_f32_16x16x32_bf16(af[m], bf[n], acc[m][n], 0, 0, 0);
    }
    __syncthreads();
  }
  const int colb = bx * 256 + wc * 64 + lo;
#pragma unroll
  for (int m = 0; m < 4; ++m) {
    int row0 = bm * 128 + wr * 64 + m * 16 + hi * 4;
#pragma unroll
    for (int n = 0; n < 4; ++n) {
      int col = colb + n * 16;
      int r3 = col >> 10;
      const float* bp = (r3 == 0) ? bq : ((r3 == 1) ? bk : bv);
      float bs = bp[col & 1023];
      if (r3 == 2) {
        // V region: write directly transposed into Vt[B*H][64][SEQ]
        int vdim = col - 2048;
        int hh = vdim >> 6, dd = vdim & 63;
        int bb = row0 >> 11, ss = row0 & 2047;
        short4v t;
#pragma unroll
        for (int j = 0; j < 4; ++j) t[j] = f2bf(acc[m][n][j] + bs);
        *(short4v*)&VtOut[((size_t)(bb * 16 + hh) * 64 + dd) * SEQ + ss] = t;
      } else {
#pragma unroll
        for (int j = 0; j < 4; ++j)
          Cout[(size_t)(row0 + j) * LDQK + col] = f2bf(acc[m][n][j] + bs);
      }
    }
  }
}

// C[M,N] = A[M,K] @ Bt[N,K]^T + bias + resid(bf16), bf16 out. 128x64 tile,
// 4 waves, dbuf. R21: counted-vmcnt async pipeline — 2 tiles in flight,
// per-step wait vmcnt(6) (tile t's 6 loads done, t+1's stay in flight),
// raw s_barrier (no vmcnt(0) drain), stage(t+2) after second barrier.
__global__ void __launch_bounds__(256, 2) gemm_n64(
    const short* __restrict__ A, const short* __restrict__ Bt,
    const float* __restrict__ b0, const short* __restrict__ resid,
    short* __restrict__ Cout, int M, int N, int K) {
  __shared__ __align__(16) short As[2][128 * 64];
  __shared__ __align__(16) short Bs[2][64 * 64];
  const int w = threadIdx.x >> 6, lane = threadIdx.x & 63;
  const int hi = lane >> 4, lo = lane & 15;
  const int bm = blockIdx.y, bn = blockIdx.x;
  const int wr = w >> 1, wc = w & 1;
  f32x4 acc[4][2] = {};
  const int nkt = K >> 6;

  auto stage = [&](int kt, int buf) {
#pragma unroll
    for (int j = 0; j < 4; ++j) {
      int c = (j * 4 + w) * 64 + lane;
      int r = c >> 3;
      int scc = (c & 7) ^ (r & 7);
      async_load16(A + (size_t)(bm * 128 + r) * K + kt * 64 + scc * 8,
                   &As[buf][(j * 4 + w) * 512]);
    }
#pragma unroll
    for (int j = 0; j < 2; ++j) {
      int c = j * 256 + w * 64 + lane;
      int r = c >> 3;
      int scc = (c & 7) ^ (r & 7);
      async_load16(Bt + (size_t)(bn * 64 + r) * K + kt * 64 + scc * 8,
                   &Bs[buf][(j * 256 + w * 64) * 8]);
    }
  };

  stage(0, 0);
  stage(1, 1);  // 12 loads in flight (2 tiles)

  for (int kt = 0; kt < nkt; ++kt) {
    const int buf = kt & 1;
    // wait only for tile kt's 6 loads; tile kt+1's 6 remain in flight
    if (kt + 1 < nkt) asm volatile("s_waitcnt vmcnt(6)" ::: "memory");
    else              asm volatile("s_waitcnt vmcnt(0)" ::: "memory");
    __builtin_amdgcn_s_barrier();  // tile kt visible to all waves
#pragma unroll
    for (int ks = 0; ks < 2; ++ks) {
      short8 af[4], bf[2];
#pragma unroll
      for (int m = 0; m < 4; ++m) {
        int row = wr * 64 + m * 16 + lo;
        int ch = (ks * 4 + hi) ^ (row & 7);
        af[m] = *(const short8*)(&As[buf][row * 64 + ch * 8]);
      }
#pragma unroll
      for (int n = 0; n < 2; ++n) {
        int row = wc * 32 + n * 16 + lo;
        int ch = (ks * 4 + hi) ^ (row & 7);
        bf[n] = *(const short8*)(&Bs[buf][row * 64 + ch * 8]);
      }
#pragma unroll
      for (int m = 0; m < 4; ++m)
#pragma unroll
        for (int n = 0; n < 2; ++n)
          acc[m][n] = __builtin_amdgcn_mfma_f32_16x16x32_bf16(af[m], bf[n], acc[m][n], 0, 0, 0);
    }
    __builtin_amdgcn_s_barrier();  // all waves done reading buf
    if (kt + 2 < nkt) stage(kt + 2, buf);  // overwrite buf for tile kt+2
  }
  const int colb = bn * 64 + wc * 32 + lo;
#pragma unroll
  for (int m = 0; m < 4; ++m) {
    int row0 = bm * 128 + wr * 64 + m * 16 + hi * 4;
#pragma unroll
    for (int n = 0; n < 2; ++n) {
      int col = colb + n * 16;
      float bs = b0[col];
#pragma unroll
      for (int j = 0; j < 4; ++j) {
        size_t idx = (size_t)(row0 + j) * N + col;
        Cout[idx] = f2bf(acc[m][n][j] + bs + bf2f(resid[idx]));
      }
    }
  }
}

// 8-wave wide-block GEMM (FF1). R21: counted-vmcnt async pipeline, 4 loads
// per stage -> vmcnt(4) mid-loop, raw barriers, stage(t+2) after reads done.
template <int EPI, bool RESID>
__global__ void __launch_bounds__(512, 2) gemm_w8d(
    const short* __restrict__ A, const short* __restrict__ Bt,
    const float* __restrict__ b0, const short* __restrict__ resid,
    short* __restrict__ Cout, int M, int N, int K) {
  __shared__ __align__(16) short As[2][128 * 64];
  __shared__ __align__(16) short Bs[2][128 * 64];
  const int tid = threadIdx.x;
  const int w = tid >> 6, lane = tid & 63;
  const int hi = lane >> 4, lo = lane & 15;
  const int bx = blockIdx.x, bm = blockIdx.y;
  const int wr = w >> 2, wc = w & 3;
  f32x4 acc[4][2] = {};
  const int nkt = K >> 6;

  auto stage = [&](int kt, int buf) {
#pragma unroll
    for (int i = 0; i < 2; ++i) {
      int c = i * 512 + tid;
      int r = c >> 3, scc = (c & 7) ^ (r & 7);
      async_load16(A + (size_t)(bm * 128 + r) * K + kt * 64 + scc * 8,
                   &As[buf][(i * 8 + w) * 512]);
    }
#pragma unroll
    for (int i = 0; i < 2; ++i) {
      int c = i * 512 + tid;
      int r = c >> 3, scc = (c & 7) ^ (r & 7);
      async_load16(Bt + (size_t)(bx * 128 + r) * K + kt * 64 + scc * 8,
                   &Bs[buf][(i * 8 + w) * 512]);
    }
  };

  stage(0, 0);
  stage(1, 1);  // 8 loads in flight (2 tiles)

  for (int kt = 0; kt < nkt; ++kt) {
    const int buf = kt & 1;
    if (kt + 1 < nkt) asm volatile("s_waitcnt vmcnt(4)" ::: "memory");
    else              asm volatile("s_waitcnt vmcnt(0)" ::: "memory");
    __builtin_amdgcn_s_barrier();
#pragma unroll
    for (int ks = 0; ks < 2; ++ks) {
      short8 af[4], bf[2];
#pragma unroll
      for (int m = 0; m < 4; ++m) {
        int row = wr * 64 + m * 16 + lo;
        int ch = (ks * 4 + hi) ^ (row & 7);
        af[m] = *(const short8*)(&As[buf][row * 64 + ch * 8]);
      }
#pragma unroll
      for (int n = 0; n < 2; ++n) {
        int row = wc * 32 + n * 16 + lo;
        int ch = (ks * 4 + hi) ^ (row & 7);
        bf[n] = *(const short8*)(&Bs[buf][row * 64 + ch * 8]);
      }
#pragma unroll
      for (int m = 0; m < 4; ++m)
#pragma unroll
        for (int n = 0; n < 2; ++n)
          acc[m][n] = __builtin_amdgcn_mfma_f32_16x16x32_bf16(af[m], bf[n], acc[m][n], 0, 0, 0);
    }
    __builtin_amdgcn_s_barrier();
    if (kt + 2 < nkt) stage(kt + 2, buf);
  }
  const int colb = bx * 128 + wc * 32 + lo;
#pragma unroll
  for (int m = 0; m < 4; ++m) {
    int row0 = bm * 128 + wr * 64 + m * 16 + hi * 4;
#pragma unroll
    for (int n = 0; n < 2; ++n) {
      int col = colb + n * 16;
      float bs = b0[col];
#pragma unroll
      for (int j = 0; j < 4; ++j) {
        size_t idx = (size_t)(row0 + j) * N + col;
        float v = acc[m][n][j] + bs;
        if (EPI == 1) v = 0.5f * v * (1.f + erff(v * 0.70710678f));
        if (RESID) v += bf2f(resid[idx]);
        Cout[idx] = f2bf(v);
      }
    }
  }
}

// Flash attention. 64 q-rows/block (4 waves x 16 rows), KVBLK=64,
// dbuf K/V one-tile-ahead prefetch, 40KB LDS, grid 1024. No-max softmax,
// XOR-swizzled K/V reads, swapped QK^T, wave-private swizzled P,
// XCD-chunked swizzle, setprio around MFMA clusters.
__global__ void __launch_bounds__(256, 2) attn_kernel(
    const short* __restrict__ Qb, const short* __restrict__ Kb,
    const short* __restrict__ Vt, short* __restrict__ ctx) {
  const int w = threadIdx.x >> 6, lane = threadIdx.x & 63;
  const int hi = lane >> 4, lo = lane & 15;
  const int tid = threadIdx.x;
  const int L = blockIdx.x;
  const int W = (L & 7) * 128 + (L >> 3);
  const int qt = W & 31, bh = W >> 5;
  const int b = bh >> 4, h = bh & 15;
  const int qbase = qt * 64 + w * 16;
  const float C = 0.18033688f;  // 0.125 * log2(e)

  __shared__ __align__(16) short Ks[2][64 * 64];  // 16KB
  __shared__ __align__(16) short Vs[2][64 * 64];  // 16KB
  __shared__ __align__(16) short P[4][16 * 64];   // 8KB (wave-private)

  const short* qp = Qb + (size_t)(b * SEQ + qbase + lo) * LDQK + h * 64;
  short8 bq[2];
#pragma unroll
  for (int c = 0; c < 2; ++c)
    bq[c] = *(const short8*)(qp + c * 32 + hi * 8);

  const short* kb = Kb + (size_t)(b * SEQ) * LDQK + h * 64;
  const short* vb = Vt + (size_t)bh * 64 * SEQ;

  auto stage = [&](int kt, int buf) {
    const short* kg = kb + (size_t)(kt * 64) * LDQK;
#pragma unroll
    for (int i = 0; i < 2; ++i) {
      int c = i * 256 + tid;
      int r = c >> 3, scc = (c & 7) ^ (r & 7);
      async_load16(kg + (size_t)r * LDQK + scc * 8,
                   &Ks[buf][(i * 256 + w * 64) * 8]);
    }
    const short* vg = vb + kt * 64;
#pragma unroll
    for (int i = 0; i < 2; ++i) {
      int c = i * 256 + tid;
      int r = c >> 3, sc2 = (c & 7) ^ (r & 7);
      async_load16(vg + (size_t)r * SEQ + sc2 * 8,
                   &Vs[buf][(i * 256 + w * 64) * 8]);
    }
  };

  stage(0, 0);
  __syncthreads();

  f32x4 o[4] = {};
  float lacc = 0.f;
  const int x7 = lo & 7;

  for (int kt = 0; kt < SEQ / 64; ++kt) {
    const int buf = kt & 1;
    if (kt + 1 < SEQ / 64) stage(kt + 1, buf ^ 1);

    f32x4 s[4] = {};
    __builtin_amdgcn_s_setprio(1);
#pragma unroll
    for (int g = 0; g < 4; ++g) {
      const short* kr = &Ks[buf][(g * 16 + lo) * 64];
      short8 ka0 = *(const short8*)(kr + ((hi) ^ x7) * 8);
      short8 ka1 = *(const short8*)(kr + ((4 + hi) ^ x7) * 8);
      s[g] = __builtin_amdgcn_mfma_f32_16x16x32_bf16(ka0, bq[0], s[g], 0, 0, 0);
      s[g] = __builtin_amdgcn_mfma_f32_16x16x32_bf16(ka1, bq[1], s[g], 0, 0, 0);
    }
    __builtin_amdgcn_s_setprio(0);
    short8 vv[2][4];
#pragma unroll
    for (int ks = 0; ks < 2; ++ks)
#pragma unroll
      for (int a = 0; a < 4; ++a)
        vv[ks][a] = *(const short8*)(&Vs[buf][(a * 16 + lo) * 64 + (((ks * 4 + hi) ^ x7) * 8)]);

    float rsg[4];
    short* pbase = &P[w][0];
#pragma unroll
    for (int g = 0; g < 4; ++g) {
      float p0 = exp2f(s[g][0] * C);
      float p1 = exp2f(s[g][1] * C);
      float p2 = exp2f(s[g][2] * C);
      float p3 = exp2f(s[g][3] * C);
      rsg[g] = (p0 + p1) + (p2 + p3);
      unsigned w0, w1;
      asm("v_cvt_pk_bf16_f32 %0, %1, %2" : "=v"(w0) : "v"(p0), "v"(p1));
      asm("v_cvt_pk_bf16_f32 %0, %1, %2" : "=v"(w1) : "v"(p2), "v"(p3));
      union { unsigned uu[2]; short4v s4; } cv;
      cv.uu[0] = w0; cv.uu[1] = w1;
      int pc = (2 * g + (hi >> 1)) ^ x7;
      *(short4v*)(pbase + lo * 64 + pc * 8 + (hi & 1) * 4) = cv.s4;
    }
    __builtin_amdgcn_s_setprio(1);
#pragma unroll
    for (int ks = 0; ks < 2; ++ks) {
      int pc = (ks * 4 + hi) ^ x7;
      short8 pa = *(const short8*)(pbase + lo * 64 + pc * 8);
#pragma unroll
      for (int a = 0; a < 4; ++a)
        o[a] = __builtin_amdgcn_mfma_f32_16x16x32_bf16(pa, vv[ks][a], o[a], 0, 0, 0);
    }
    __builtin_amdgcn_s_setprio(0);
    lacc += (rsg[0] + rsg[1]) + (rsg[2] + rsg[3]);
    __syncthreads();
  }
  lacc += __shfl_xor(lacc, 16);
  lacc += __shfl_xor(lacc, 32);
#pragma unroll
  for (int j = 0; j < 4; ++j) {
    float lj = __shfl(lacc, hi * 4 + j);
    float inv = 1.f / lj;
    int row = qbase + hi * 4 + j;
#pragma unroll
    for (int a = 0; a < 4; ++a)
      ctx[(size_t)(b * SEQ + row) * DM + h * 64 + a * 16 + lo] = f2bf(o[a][j] * inv);
  }
}

// out = LN(in)*g + beta, in is bf16 (already residual-summed).
// Writes f32 outf and/or bf16 outb (nullable).
__global__ void __launch_bounds__(256) ln_bf16(
    const short* __restrict__ in, const float* __restrict__ g,
    const float* __restrict__ beta, float* __restrict__ outf,
    short* __restrict__ outb) {
  const int row = blockIdx.x;
  const int t = threadIdx.x;
  const size_t base = (size_t)row * DM;
  short4v iv = ((const short4v*)(in + base))[t];
  f32x4 v;
#pragma unroll
  for (int j = 0; j < 4; ++j) v[j] = bf2f(iv[j]);
  float s = v[0] + v[1] + v[2] + v[3];
  float s2 = v[0] * v[0] + v[1] * v[1] + v[2] * v[2] + v[3] * v[3];
#pragma unroll
  for (int off = 1; off < 64; off <<= 1) {
    s += __shfl_xor(s, off);
    s2 += __shfl_xor(s2, off);
  }
  __shared__ float rs[4], rs2[4];
  if ((t & 63) == 0) { rs[t >> 6] = s; rs2[t >> 6] = s2; }
  __syncthreads();
  s = rs[0] + rs[1] + rs[2] + rs[3];
  s2 = rs2[0] + rs2[1] + rs2[2] + rs2[3];
  float mu = s * (1.f / DM);
  float var = s2 * (1.f / DM) - mu * mu;
  float rstd = rsqrtf(var + 1e-5f);
  f32x4 gv = ((const f32x4*)g)[t];
  f32x4 bv = ((const f32x4*)beta)[t];
  f32x4 ov;
#pragma unroll
  for (int j = 0; j < 4; ++j) ov[j] = (v[j] - mu) * rstd * gv[j] + bv[j];
  if (outf) ((f32x4*)(outf + base))[t] = ov;
  if (outb) {
    short4v sb;
#pragma unroll
    for (int j = 0; j < 4; ++j) sb[j] = f2bf(ov[j]);
    ((short4v*)(outb + base))[t] = sb;
  }
}

extern "C" void kernel_launch(void* const* d_in, const int* in_sizes, int n_in,
                              void* d_out, int out_size, void* d_ws, size_t ws_size,
                              hipStream_t stream) {
  (void)in_sizes; (void)n_in; (void)out_size; (void)ws_size;
  const float* x   = (const float*)d_in[0];
  const float* Wq  = (const float*)d_in[1];
  const float* bq  = (const float*)d_in[2];
  const float* Wk  = (const float*)d_in[3];
  const float* bk  = (const float*)d_in[4];
  const float* Wv  = (const float*)d_in[5];
  const float* bv  = (const float*)d_in[6];
  const float* Wo  = (const float*)d_in[7];
  const float* bo  = (const float*)d_in[8];
  const float* g1  = (const float*)d_in[9];
  const float* b1  = (const float*)d_in[10];
  const float* Wf1 = (const float*)d_in[11];
  const float* bf1 = (const float*)d_in[12];
  const float* Wf2 = (const float*)d_in[13];
  const float* bf2 = (const float*)d_in[14];
  const float* g2  = (const float*)d_in[15];
  const float* b2  = (const float*)d_in[16];

  char* ws = (char*)d_ws;
  const size_t MB = 1u << 20;
  short* Wqkv = (short*)(ws + 0 * MB);    // [3072][1024] bf16, 6 MB
  short* Wto  = (short*)(ws + 6 * MB);    // 2 MB
  short* Wtf1 = (short*)(ws + 8 * MB);    // 4 MB
  short* Wtf2 = (short*)(ws + 12 * MB);   // 4 MB
  short* xb   = (short*)(ws + 16 * MB);   // 8 MB
  short* QKV  = (short*)(ws + 24 * MB);   // [4096][3072] bf16, 24 MB (V third unused)
  short* Vt   = (short*)(ws + 48 * MB);   // 8 MB (written by QKV gemm epilogue)
  short* ctxb = (short*)(ws + 56 * MB);   // 8 MB
  short* aout = (short*)(ws + 64 * MB);   // bf16 (x + ctx@Wo + bo), 8 MB
  short* x1b  = (short*)(ws + 72 * MB);   // bf16 LN1 output, 8 MB
  short* hb   = QKV;                       // QKV dead after attention
  short* ffo  = (short*)(ws + 48 * MB);   // bf16 (x1 + ffn), over Vt (dead)

  prep_all<<<dim3(64, 64, 7), dim3(32, 8), 0, stream>>>(
      Wq, Wk, Wv, Wo, Wf1, Wf2, x, Wqkv, Wto, Wtf1, Wtf2, xb);

  gemm_qkv8<<<dim3(12, 32), 512, 0, stream>>>(xb, Wqkv, bq, bk, bv, QKV, Vt);

  attn_kernel<<<dim3(1024), 256, 0, stream>>>(QKV, QKV + 1024, Vt, ctxb);

  // aout = x + ctx@Wo + bo (residual fused)
  gemm_n64<<<dim3(16, 32), 256, 0, stream>>>(ctxb, Wto, bo, xb, aout, NTOK, 1024, 1024);
  ln_bf16<<<4096, 256, 0, stream>>>(aout, g1, b1, nullptr, x1b);
  // FF1: 8-wave wide-block async pipeline
  gemm_w8d<1, false><<<dim3(16, 32), 512, 0, stream>>>(
      x1b, Wtf1, bf1, nullptr, hb, NTOK, 2048, 1024);
  // ffo = x1 + h@Wf2 + bf2 (residual fused)
  gemm_n64<<<dim3(16, 32), 256, 0, stream>>>(hb, Wtf2, bf2, x1b, ffo, NTOK, 1024, 2048);
  ln_bf16<<<4096, 256, 0, stream>>>(ffo, g2, b2, (float*)d_out, nullptr);
}

// Round 22
// 203.465 us; speedup vs baseline: 1.0236x; 1.0008x over previous
//
#include <hip/hip_runtime.h>

#define SEQ 2048
#define NTOK 4096
#define DM 1024
#define LDQK 3072

typedef __attribute__((ext_vector_type(4))) float f32x4;
typedef __attribute__((ext_vector_type(8))) short short8;
typedef __attribute__((ext_vector_type(4))) short short4v;

__device__ __forceinline__ short f2bf(float f) {
  union { float f; unsigned u; } x; x.f = f;
  unsigned r = x.u + 0x7fffu + ((x.u >> 16) & 1u);
  return (short)(r >> 16);
}

__device__ __forceinline__ float bf2f(short s) {
  union { unsigned u; float f; } x;
  x.u = ((unsigned)(unsigned short)s) << 16;
  return x.f;
}

__device__ __forceinline__ void async_load16(const void* g, void* l) {
  __builtin_amdgcn_global_load_lds(
      (const __attribute__((address_space(1))) void*)g,
      (__attribute__((address_space(3))) void*)l, 16, 0, 0);
}

// All prep in one launch. z=0..3: 1024x1024 W transposes; z=4: Wf1; z=5: Wf2;
// z=6: x f32->bf16 cast. Block (32,8).
__global__ void __launch_bounds__(256) prep_all(
    const float* __restrict__ Wq, const float* __restrict__ Wk,
    const float* __restrict__ Wv, const float* __restrict__ Wo,
    const float* __restrict__ Wf1, const float* __restrict__ Wf2,
    const float* __restrict__ x,
    short* __restrict__ Wqkv, short* __restrict__ Wto,
    short* __restrict__ Wtf1, short* __restrict__ Wtf2,
    short* __restrict__ xb) {
  const int z = blockIdx.z;
  const int tx = threadIdx.x, ty = threadIdx.y;
  if (z == 6) {
    int blk = blockIdx.y * 64 + blockIdx.x;
    int i = blk * 256 + ty * 32 + tx;
    f32x4 v = ((const f32x4*)x)[i];
    short4v o;
#pragma unroll
    for (int j = 0; j < 4; ++j) o[j] = f2bf(v[j]);
    ((short4v*)xb)[i] = o;
    return;
  }
  const float* in;
  short* out;
  int K, N;
  switch (z) {
    case 0: in = Wq;  out = Wqkv;               K = 1024; N = 1024; break;
    case 1: in = Wk;  out = Wqkv + 1024 * 1024; K = 1024; N = 1024; break;
    case 2: in = Wv;  out = Wqkv + 2048 * 1024; K = 1024; N = 1024; break;
    case 3: in = Wo;  out = Wto;                K = 1024; N = 1024; break;
    case 4: in = Wf1; out = Wtf1;               K = 1024; N = 2048; break;
    default: in = Wf2; out = Wtf2;              K = 2048; N = 1024; break;
  }
  if (blockIdx.x * 32 >= N || blockIdx.y * 32 >= K) return;
  __shared__ float t[32][33];
  const int n = blockIdx.x * 32 + tx;
#pragma unroll
  for (int i = 0; i < 4; ++i) {
    int k = blockIdx.y * 32 + ty + i * 8;
    t[ty + i * 8][tx] = in[(size_t)k * N + n];
  }
  __syncthreads();
  const int k2 = blockIdx.y * 32 + tx;
#pragma unroll
  for (int i = 0; i < 4; ++i) {
    int n2 = blockIdx.x * 32 + ty + i * 8;
    out[(size_t)n2 * K + k2] = f2bf(t[tx][ty + i * 8]);
  }
}

// QKV fused GEMM, 8 waves / 512 threads, block output 128x256.
// grid (12, 32). V region written directly transposed into Vt[B*H][64][SEQ].
__global__ void __launch_bounds__(512, 2) gemm_qkv8(
    const short* __restrict__ A, const short* __restrict__ Bt,
    const float* __restrict__ bq, const float* __restrict__ bk,
    const float* __restrict__ bv, short* __restrict__ Cout,
    short* __restrict__ VtOut) {
  __shared__ __align__(16) short As[128 * 64];   // 16KB
  __shared__ __align__(16) short Bs[256 * 64];   // 32KB
  const int tid = threadIdx.x;
  const int w = tid >> 6, lane = tid & 63;
  const int hi = lane >> 4, lo = lane & 15;
  const int bx = blockIdx.x, bm = blockIdx.y;
  const int wr = w >> 2, wc = w & 3;  // 2M x 4N wave grid; per-wave 64x64
  f32x4 acc[4][4] = {};

  for (int kt = 0; kt < 16; ++kt) {
#pragma unroll
    for (int i = 0; i < 2; ++i) {
      int c = i * 512 + tid;
      int r = c >> 3, scc = (c & 7) ^ (r & 7);
      async_load16(A + (size_t)(bm * 128 + r) * 1024 + kt * 64 + scc * 8,
                   &As[(i * 8 + w) * 512]);
    }
#pragma unroll
    for (int i = 0; i < 4; ++i) {
      int c = i * 512 + tid;
      int r = c >> 3, scc = (c & 7) ^ (r & 7);
      async_load16(Bt + (size_t)(bx * 256 + r) * 1024 + kt * 64 + scc * 8,
                   &Bs[(i * 8 + w) * 512]);
    }
    __syncthreads();
#pragma unroll
    for (int ks = 0; ks < 2; ++ks) {
      short8 af[4], bf[4];
#pragma unroll
      for (int m = 0; m < 4; ++m) {
        int row = wr * 64 + m * 16 + lo;
        int ch = (ks * 4 + hi) ^ (row & 7);
        af[m] = *(const short8*)(&As[row * 64 + ch * 8]);
      }
#pragma unroll
      for (int n = 0; n < 4; ++n) {
        int row = wc * 64 + n * 16 + lo;
        int ch = (ks * 4 + hi) ^ (row & 7);
        bf[n] = *(const short8*)(&Bs[row * 64 + ch * 8]);
      }
#pragma unroll
      for (int m = 0; m < 4; ++m)
#pragma unroll
        for (int n = 0; n < 4; ++n)
          acc[m][n] = __builtin_amdgcn_mfma_f32_16x16x32_bf16(af[m], bf[n], acc[m][n], 0, 0, 0);
    }
    __syncthreads();
  }
  const int colb = bx * 256 + wc * 64 + lo;
#pragma unroll
  for (int m = 0; m < 4; ++m) {
    int row0 = bm * 128 + wr * 64 + m * 16 + hi * 4;
#pragma unroll
    for (int n = 0; n < 4; ++n) {
      int col = colb + n * 16;
      int r3 = col >> 10;
      const float* bp = (r3 == 0) ? bq : ((r3 == 1) ? bk : bv);
      float bs = bp[col & 1023];
      if (r3 == 2) {
        // V region: write directly transposed into Vt[B*H][64][SEQ]
        int vdim = col - 2048;
        int hh = vdim >> 6, dd = vdim & 63;
        int bb = row0 >> 11, ss = row0 & 2047;
        short4v t;
#pragma unroll
        for (int j = 0; j < 4; ++j) t[j] = f2bf(acc[m][n][j] + bs);
        *(short4v*)&VtOut[((size_t)(bb * 16 + hh) * 64 + dd) * SEQ + ss] = t;
      } else {
#pragma unroll
        for (int j = 0; j < 4; ++j)
          Cout[(size_t)(row0 + j) * LDQK + col] = f2bf(acc[m][n][j] + bs);
      }
    }
  }
}

// C[M,N] = A[M,K] @ Bt[N,K]^T + bias + resid(bf16), bf16 out. 128x64 tile,
// 4 waves, dbuf. R21: counted-vmcnt async pipeline — 2 tiles in flight,
// per-step wait vmcnt(6) (tile t's 6 loads done, t+1's stay in flight),
// raw s_barrier (no vmcnt(0) drain), stage(t+2) after second barrier.
__global__ void __launch_bounds__(256, 2) gemm_n64(
    const short* __restrict__ A, const short* __restrict__ Bt,
    const float* __restrict__ b0, const short* __restrict__ resid,
    short* __restrict__ Cout, int M, int N, int K) {
  __shared__ __align__(16) short As[2][128 * 64];
  __shared__ __align__(16) short Bs[2][64 * 64];
  const int w = threadIdx.x >> 6, lane = threadIdx.x & 63;
  const int hi = lane >> 4, lo = lane & 15;
  const int bm = blockIdx.y, bn = blockIdx.x;
  const int wr = w >> 1, wc = w & 1;
  f32x4 acc[4][2] = {};
  const int nkt = K >> 6;

  auto stage = [&](int kt, int buf) {
#pragma unroll
    for (int j = 0; j < 4; ++j) {
      int c = (j * 4 + w) * 64 + lane;
      int r = c >> 3;
      int scc = (c & 7) ^ (r & 7);
      async_load16(A + (size_t)(bm * 128 + r) * K + kt * 64 + scc * 8,
                   &As[buf][(j * 4 + w) * 512]);
    }
#pragma unroll
    for (int j = 0; j < 2; ++j) {
      int c = j * 256 + w * 64 + lane;
      int r = c >> 3;
      int scc = (c & 7) ^ (r & 7);
      async_load16(Bt + (size_t)(bn * 64 + r) * K + kt * 64 + scc * 8,
                   &Bs[buf][(j * 256 + w * 64) * 8]);
    }
  };

  stage(0, 0);
  stage(1, 1);  // 12 loads in flight (2 tiles)

  for (int kt = 0; kt < nkt; ++kt) {
    const int buf = kt & 1;
    // wait only for tile kt's 6 loads; tile kt+1's 6 remain in flight
    if (kt + 1 < nkt) asm volatile("s_waitcnt vmcnt(6)" ::: "memory");
    else              asm volatile("s_waitcnt vmcnt(0)" ::: "memory");
    __builtin_amdgcn_s_barrier();  // tile kt visible to all waves
#pragma unroll
    for (int ks = 0; ks < 2; ++ks) {
      short8 af[4], bf[2];
#pragma unroll
      for (int m = 0; m < 4; ++m) {
        int row = wr * 64 + m * 16 + lo;
        int ch = (ks * 4 + hi) ^ (row & 7);
        af[m] = *(const short8*)(&As[buf][row * 64 + ch * 8]);
      }
#pragma unroll
      for (int n = 0; n < 2; ++n) {
        int row = wc * 32 + n * 16 + lo;
        int ch = (ks * 4 + hi) ^ (row & 7);
        bf[n] = *(const short8*)(&Bs[buf][row * 64 + ch * 8]);
      }
#pragma unroll
      for (int m = 0; m < 4; ++m)
#pragma unroll
        for (int n = 0; n < 2; ++n)
          acc[m][n] = __builtin_amdgcn_mfma_f32_16x16x32_bf16(af[m], bf[n], acc[m][n], 0, 0, 0);
    }
    __builtin_amdgcn_s_barrier();  // all waves done reading buf
    if (kt + 2 < nkt) stage(kt + 2, buf);  // overwrite buf for tile kt+2
  }
  const int colb = bn * 64 + wc * 32 + lo;
#pragma unroll
  for (int m = 0; m < 4; ++m) {
    int row0 = bm * 128 + wr * 64 + m * 16 + hi * 4;
#pragma unroll
    for (int n = 0; n < 2; ++n) {
      int col = colb + n * 16;
      float bs = b0[col];
#pragma unroll
      for (int j = 0; j < 4; ++j) {
        size_t idx = (size_t)(row0 + j) * N + col;
        Cout[idx] = f2bf(acc[m][n][j] + bs + bf2f(resid[idx]));
      }
    }
  }
}

// 8-wave wide-block GEMM (FF1). R21: counted-vmcnt async pipeline, 4 loads
// per stage -> vmcnt(4) mid-loop, raw barriers, stage(t+2) after reads done.
template <int EPI, bool RESID>
__global__ void __launch_bounds__(512, 2) gemm_w8d(
    const short* __restrict__ A, const short* __restrict__ Bt,
    const float* __restrict__ b0, const short* __restrict__ resid,
    short* __restrict__ Cout, int M, int N, int K) {
  __shared__ __align__(16) short As[2][128 * 64];
  __shared__ __align__(16) short Bs[2][128 * 64];
  const int tid = threadIdx.x;
  const int w = tid >> 6, lane = tid & 63;
  const int hi = lane >> 4, lo = lane & 15;
  const int bx = blockIdx.x, bm = blockIdx.y;
  const int wr = w >> 2, wc = w & 3;
  f32x4 acc[4][2] = {};
  const int nkt = K >> 6;

  auto stage = [&](int kt, int buf) {
#pragma unroll
    for (int i = 0; i < 2; ++i) {
      int c = i * 512 + tid;
      int r = c >> 3, scc = (c & 7) ^ (r & 7);
      async_load16(A + (size_t)(bm * 128 + r) * K + kt * 64 + scc * 8,
                   &As[buf][(i * 8 + w) * 512]);
    }
#pragma unroll
    for (int i = 0; i < 2; ++i) {
      int c = i * 512 + tid;
      int r = c >> 3, scc = (c & 7) ^ (r & 7);
      async_load16(Bt + (size_t)(bx * 128 + r) * K + kt * 64 + scc * 8,
                   &Bs[buf][(i * 8 + w) * 512]);
    }
  };

  stage(0, 0);
  stage(1, 1);  // 8 loads in flight (2 tiles)

  for (int kt = 0; kt < nkt; ++kt) {
    const int buf = kt & 1;
    if (kt + 1 < nkt) asm volatile("s_waitcnt vmcnt(4)" ::: "memory");
    else              asm volatile("s_waitcnt vmcnt(0)" ::: "memory");
    __builtin_amdgcn_s_barrier();
#pragma unroll
    for (int ks = 0; ks < 2; ++ks) {
      short8 af[4], bf[2];
#pragma unroll
      for (int m = 0; m < 4; ++m) {
        int row = wr * 64 + m * 16 + lo;
        int ch = (ks * 4 + hi) ^ (row & 7);
        af[m] = *(const short8*)(&As[buf][row * 64 + ch * 8]);
      }
#pragma unroll
      for (int n = 0; n < 2; ++n) {
        int row = wc * 32 + n * 16 + lo;
        int ch = (ks * 4 + hi) ^ (row & 7);
        bf[n] = *(const short8*)(&Bs[buf][row * 64 + ch * 8]);
      }
#pragma unroll
      for (int m = 0; m < 4; ++m)
#pragma unroll
        for (int n = 0; n < 2; ++n)
          acc[m][n] = __builtin_amdgcn_mfma_f32_16x16x32_bf16(af[m], bf[n], acc[m][n], 0, 0, 0);
    }
    __builtin_amdgcn_s_barrier();
    if (kt + 2 < nkt) stage(kt + 2, buf);
  }
  const int colb = bx * 128 + wc * 32 + lo;
#pragma unroll
  for (int m = 0; m < 4; ++m) {
    int row0 = bm * 128 + wr * 64 + m * 16 + hi * 4;
#pragma unroll
    for (int n = 0; n < 2; ++n) {
      int col = colb + n * 16;
      float bs = b0[col];
#pragma unroll
      for (int j = 0; j < 4; ++j) {
        size_t idx = (size_t)(row0 + j) * N + col;
        float v = acc[m][n][j] + bs;
        if (EPI == 1) v = 0.5f * v * (1.f + erff(v * 0.70710678f));
        if (RESID) v += bf2f(resid[idx]);
        Cout[idx] = f2bf(v);
      }
    }
  }
}

// Flash attention. 64 q-rows/block (4 waves x 16 rows), KVBLK=64,
// dbuf K/V one-tile-ahead prefetch, 40KB LDS, grid 1024. No-max softmax,
// XOR-swizzled K/V reads, swapped QK^T, wave-private swizzled P,
// XCD-chunked swizzle, setprio around MFMA clusters.
__global__ void __launch_bounds__(256, 2) attn_kernel(
    const short* __restrict__ Qb, const short* __restrict__ Kb,
    const short* __restrict__ Vt, short* __restrict__ ctx) {
  const int w = threadIdx.x >> 6, lane = threadIdx.x & 63;
  const int hi = lane >> 4, lo = lane & 15;
  const int tid = threadIdx.x;
  const int L = blockIdx.x;
  const int W = (L & 7) * 128 + (L >> 3);
  const int qt = W & 31, bh = W >> 5;
  const int b = bh >> 4, h = bh & 15;
  const int qbase = qt * 64 + w * 16;
  const float C = 0.18033688f;  // 0.125 * log2(e)

  __shared__ __align__(16) short Ks[2][64 * 64];  // 16KB
  __shared__ __align__(16) short Vs[2][64 * 64];  // 16KB
  __shared__ __align__(16) short P[4][16 * 64];   // 8KB (wave-private)

  const short* qp = Qb + (size_t)(b * SEQ + qbase + lo) * LDQK + h * 64;
  short8 bq[2];
#pragma unroll
  for (int c = 0; c < 2; ++c)
    bq[c] = *(const short8*)(qp + c * 32 + hi * 8);

  const short* kb = Kb + (size_t)(b * SEQ) * LDQK + h * 64;
  const short* vb = Vt + (size_t)bh * 64 * SEQ;

  auto stage = [&](int kt, int buf) {
    const short* kg = kb + (size_t)(kt * 64) * LDQK;
#pragma unroll
    for (int i = 0; i < 2; ++i) {
      int c = i * 256 + tid;
      int r = c >> 3, scc = (c & 7) ^ (r & 7);
      async_load16(kg + (size_t)r * LDQK + scc * 8,
                   &Ks[buf][(i * 256 + w * 64) * 8]);
    }
    const short* vg = vb + kt * 64;
#pragma unroll
    for (int i = 0; i < 2; ++i) {
      int c = i * 256 + tid;
      int r = c >> 3, sc2 = (c & 7) ^ (r & 7);
      async_load16(vg + (size_t)r * SEQ + sc2 * 8,
                   &Vs[buf][(i * 256 + w * 64) * 8]);
    }
  };

  stage(0, 0);
  __syncthreads();

  f32x4 o[4] = {};
  float lacc = 0.f;
  const int x7 = lo & 7;

  for (int kt = 0; kt < SEQ / 64; ++kt) {
    const int buf = kt & 1;
    if (kt + 1 < SEQ / 64) stage(kt + 1, buf ^ 1);

    f32x4 s[4] = {};
    __builtin_amdgcn_s_setprio(1);
#pragma unroll
    for (int g = 0; g < 4; ++g) {
      const short* kr = &Ks[buf][(g * 16 + lo) * 64];
      short8 ka0 = *(const short8*)(kr + ((hi) ^ x7) * 8);
      short8 ka1 = *(const short8*)(kr + ((4 + hi) ^ x7) * 8);
      s[g] = __builtin_amdgcn_mfma_f32_16x16x32_bf16(ka0, bq[0], s[g], 0, 0, 0);
      s[g] = __builtin_amdgcn_mfma_f32_16x16x32_bf16(ka1, bq[1], s[g], 0, 0, 0);
    }
    __builtin_amdgcn_s_setprio(0);
    short8 vv[2][4];
#pragma unroll
    for (int ks = 0; ks < 2; ++ks)
#pragma unroll
      for (int a = 0; a < 4; ++a)
        vv[ks][a] = *(const short8*)(&Vs[buf][(a * 16 + lo) * 64 + (((ks * 4 + hi) ^ x7) * 8)]);

    float rsg[4];
    short* pbase = &P[w][0];
#pragma unroll
    for (int g = 0; g < 4; ++g) {
      float p0 = exp2f(s[g][0] * C);
      float p1 = exp2f(s[g][1] * C);
      float p2 = exp2f(s[g][2] * C);
      float p3 = exp2f(s[g][3] * C);
      rsg[g] = (p0 + p1) + (p2 + p3);
      unsigned w0, w1;
      asm("v_cvt_pk_bf16_f32 %0, %1, %2" : "=v"(w0) : "v"(p0), "v"(p1));
      asm("v_cvt_pk_bf16_f32 %0, %1, %2" : "=v"(w1) : "v"(p2), "v"(p3));
      union { unsigned uu[2]; short4v s4; } cv;
      cv.uu[0] = w0; cv.uu[1] = w1;
      int pc = (2 * g + (hi >> 1)) ^ x7;
      *(short4v*)(pbase + lo * 64 + pc * 8 + (hi & 1) * 4) = cv.s4;
    }
    __builtin_amdgcn_s_setprio(1);
#pragma unroll
    for (int ks = 0; ks < 2; ++ks) {
      int pc = (ks * 4 + hi) ^ x7;
      short8 pa = *(const short8*)(pbase + lo * 64 + pc * 8);
#pragma unroll
      for (int a = 0; a < 4; ++a)
        o[a] = __builtin_amdgcn_mfma_f32_16x16x32_bf16(pa, vv[ks][a], o[a], 0, 0, 0);
    }
    __builtin_amdgcn_s_setprio(0);
    lacc += (rsg[0] + rsg[1]) + (rsg[2] + rsg[3]);
    __syncthreads();
  }
  lacc += __shfl_xor(lacc, 16);
  lacc += __shfl_xor(lacc, 32);
#pragma unroll
  for (int j = 0; j < 4; ++j) {
    float lj = __shfl(lacc, hi * 4 + j);
    float inv = 1.f / lj;
    int row = qbase + hi * 4 + j;
#pragma unroll
    for (int a = 0; a < 4; ++a)
      ctx[(size_t)(b * SEQ + row) * DM + h * 64 + a * 16 + lo] = f2bf(o[a][j] * inv);
  }
}

// out = LN(in)*g + beta, in is bf16 (already residual-summed).
// Writes f32 outf and/or bf16 outb (nullable).
__global__ void __launch_bounds__(256) ln_bf16(
    const short* __restrict__ in, const float* __restrict__ g,
    const float* __restrict__ beta, float* __restrict__ outf,
    short* __restrict__ outb) {
  const int row = blockIdx.x;
  const int t = threadIdx.x;
  const size_t base = (size_t)row * DM;
  short4v iv = ((const short4v*)(in + base))[t];
  f32x4 v;
#pragma unroll
  for (int j = 0; j < 4; ++j) v[j] = bf2f(iv[j]);
  float s = v[0] + v[1] + v[2] + v[3];
  float s2 = v[0] * v[0] + v[1] * v[1] + v[2] * v[2] + v[3] * v[3];
#pragma unroll
  for (int off = 1; off < 64; off <<= 1) {
    s += __shfl_xor(s, off);
    s2 += __shfl_xor(s2, off);
  }
  __shared__ float rs[4], rs2[4];
  if ((t & 63) == 0) { rs[t >> 6] = s; rs2[t >> 6] = s2; }
  __syncthreads();
  s = rs[0] + rs[1] + rs[2] + rs[3];
  s2 = rs2[0] + rs2[1] + rs2[2] + rs2[3];
  float mu = s * (1.f / DM);
  float var = s2 * (1.f / DM) - mu * mu;
  float rstd = rsqrtf(var + 1e-5f);
  f32x4 gv = ((const f32x4*)g)[t];
  f32x4 bv = ((const f32x4*)beta)[t];
  f32x4 ov;
#pragma unroll
  for (int j = 0; j < 4; ++j) ov[j] = (v[j] - mu) * rstd * gv[j] + bv[j];
  if (outf) ((f32x4*)(outf + base))[t] = ov;
  if (outb) {
    short4v sb;
#pragma unroll
    for (int j = 0; j < 4; ++j) sb[j] = f2bf(ov[j]);
    ((short4v*)(outb + base))[t] = sb;
  }
}

extern "C" void kernel_launch(void* const* d_in, const int* in_sizes, int n_in,
                              void* d_out, int out_size, void* d_ws, size_t ws_size,
                              hipStream_t stream) {
  (void)in_sizes; (void)n_in; (void)out_size; (void)ws_size;
  const float* x   = (const float*)d_in[0];
  const float* Wq  = (const float*)d_in[1];
  const float* bq  = (const float*)d_in[2];
  const float* Wk  = (const float*)d_in[3];
  const float* bk  = (const float*)d_in[4];
  const float* Wv  = (const float*)d_in[5];
  const float* bv  = (const float*)d_in[6];
  const float* Wo  = (const float*)d_in[7];
  const float* bo  = (const float*)d_in[8];
  const float* g1  = (const float*)d_in[9];
  const float* b1  = (const float*)d_in[10];
  const float* Wf1 = (const float*)d_in[11];
  const float* bf1 = (const float*)d_in[12];
  const float* Wf2 = (const float*)d_in[13];
  const float* bf2 = (const float*)d_in[14];
  const float* g2  = (const float*)d_in[15];
  const float* b2  = (const float*)d_in[16];

  char* ws = (char*)d_ws;
  const size_t MB = 1u << 20;
  short* Wqkv = (short*)(ws + 0 * MB);    // [3072][1024] bf16, 6 MB
  short* Wto  = (short*)(ws + 6 * MB);    // 2 MB
  short* Wtf1 = (short*)(ws + 8 * MB);    // 4 MB
  short* Wtf2 = (short*)(ws + 12 * MB);   // 4 MB
  short* xb   = (short*)(ws + 16 * MB);   // 8 MB
  short* QKV  = (short*)(ws + 24 * MB);   // [4096][3072] bf16, 24 MB (V third unused)
  short* Vt   = (short*)(ws + 48 * MB);   // 8 MB (written by QKV gemm epilogue)
  short* ctxb = (short*)(ws + 56 * MB);   // 8 MB
  short* aout = (short*)(ws + 64 * MB);   // bf16 (x + ctx@Wo + bo), 8 MB
  short* x1b  = (short*)(ws + 72 * MB);   // bf16 LN1 output, 8 MB
  short* hb   = QKV;                       // QKV dead after attention
  short* ffo  = (short*)(ws + 48 * MB);   // bf16 (x1 + ffn), over Vt (dead)

  prep_all<<<dim3(64, 64, 7), dim3(32, 8), 0, stream>>>(
      Wq, Wk, Wv, Wo, Wf1, Wf2, x, Wqkv, Wto, Wtf1, Wtf2, xb);

  gemm_qkv8<<<dim3(12, 32), 512, 0, stream>>>(xb, Wqkv, bq, bk, bv, QKV, Vt);

  attn_kernel<<<dim3(1024), 256, 0, stream>>>(QKV, QKV + 1024, Vt, ctxb);

  // aout = x + ctx@Wo + bo (residual fused)
  gemm_n64<<<dim3(16, 32), 256, 0, stream>>>(ctxb, Wto, bo, xb, aout, NTOK, 1024, 1024);
  ln_bf16<<<4096, 256, 0, stream>>>(aout, g1, b1, nullptr, x1b);
  // FF1: 8-wave wide-block async pipeline
  gemm_w8d<1, false><<<dim3(16, 32), 512, 0, stream>>>(
      x1b, Wtf1, bf1, nullptr, hb, NTOK, 2048, 1024);
  // ffo = x1 + h@Wf2 + bf2 (residual fused)
  gemm_n64<<<dim3(16, 32), 256, 0, stream>>>(hb, Wtf2, bf2, x1b, ffo, NTOK, 1024, 2048);
  ln_bf16<<<4096, 256, 0, stream>>>(ffo, g2, b2, (float*)d_out, nullptr);
}

// Round 23
// 189.677 us; speedup vs baseline: 1.0980x; 1.0727x over previous
//
#include <hip/hip_runtime.h>

#define SEQ 2048
#define NTOK 4096
#define DM 1024
#define LDQK 3072

typedef __attribute__((ext_vector_type(4))) float f32x4;
typedef __attribute__((ext_vector_type(8))) short short8;
typedef __attribute__((ext_vector_type(4))) short short4v;

__device__ __forceinline__ short f2bf(float f) {
  union { float f; unsigned u; } x; x.f = f;
  unsigned r = x.u + 0x7fffu + ((x.u >> 16) & 1u);
  return (short)(r >> 16);
}

__device__ __forceinline__ float bf2f(short s) {
  union { unsigned u; float f; } x;
  x.u = ((unsigned)(unsigned short)s) << 16;
  return x.f;
}

__device__ __forceinline__ float fexp2(float x) {
  float r;
  asm("v_exp_f32 %0, %1" : "=v"(r) : "v"(x));
  return r;
}

__device__ __forceinline__ void async_load16(const void* g, void* l) {
  __builtin_amdgcn_global_load_lds(
      (const __attribute__((address_space(1))) void*)g,
      (__attribute__((address_space(3))) void*)l, 16, 0, 0);
}

// All prep in one launch. z=0..3: 1024x1024 W transposes; z=4: Wf1; z=5: Wf2;
// z=6: x f32->bf16 cast. Block (32,8).
__global__ void __launch_bounds__(256) prep_all(
    const float* __restrict__ Wq, const float* __restrict__ Wk,
    const float* __restrict__ Wv, const float* __restrict__ Wo,
    const float* __restrict__ Wf1, const float* __restrict__ Wf2,
    const float* __restrict__ x,
    short* __restrict__ Wqkv, short* __restrict__ Wto,
    short* __restrict__ Wtf1, short* __restrict__ Wtf2,
    short* __restrict__ xb) {
  const int z = blockIdx.z;
  const int tx = threadIdx.x, ty = threadIdx.y;
  if (z == 6) {
    int blk = blockIdx.y * 64 + blockIdx.x;
    int i = blk * 256 + ty * 32 + tx;
    f32x4 v = ((const f32x4*)x)[i];
    short4v o;
#pragma unroll
    for (int j = 0; j < 4; ++j) o[j] = f2bf(v[j]);
    ((short4v*)xb)[i] = o;
    return;
  }
  const float* in;
  short* out;
  int K, N;
  switch (z) {
    case 0: in = Wq;  out = Wqkv;               K = 1024; N = 1024; break;
    case 1: in = Wk;  out = Wqkv + 1024 * 1024; K = 1024; N = 1024; break;
    case 2: in = Wv;  out = Wqkv + 2048 * 1024; K = 1024; N = 1024; break;
    case 3: in = Wo;  out = Wto;                K = 1024; N = 1024; break;
    case 4: in = Wf1; out = Wtf1;               K = 1024; N = 2048; break;
    default: in = Wf2; out = Wtf2;              K = 2048; N = 1024; break;
  }
  if (blockIdx.x * 32 >= N || blockIdx.y * 32 >= K) return;
  __shared__ float t[32][33];
  const int n = blockIdx.x * 32 + tx;
#pragma unroll
  for (int i = 0; i < 4; ++i) {
    int k = blockIdx.y * 32 + ty + i * 8;
    t[ty + i * 8][tx] = in[(size_t)k * N + n];
  }
  __syncthreads();
  const int k2 = blockIdx.y * 32 + tx;
#pragma unroll
  for (int i = 0; i < 4; ++i) {
    int n2 = blockIdx.x * 32 + ty + i * 8;
    out[(size_t)n2 * K + k2] = f2bf(t[tx][ty + i * 8]);
  }
}

// QKV fused GEMM, 8 waves / 512 threads, block output 128x256.
// grid (12, 32). V region written directly transposed into Vt[B*H][64][SEQ].
__global__ void __launch_bounds__(512, 2) gemm_qkv8(
    const short* __restrict__ A, const short* __restrict__ Bt,
    const float* __restrict__ bq, const float* __restrict__ bk,
    const float* __restrict__ bv, short* __restrict__ Cout,
    short* __restrict__ VtOut) {
  __shared__ __align__(16) short As[128 * 64];   // 16KB
  __shared__ __align__(16) short Bs[256 * 64];   // 32KB
  const int tid = threadIdx.x;
  const int w = tid >> 6, lane = tid & 63;
  const int hi = lane >> 4, lo = lane & 15;
  const int bx = blockIdx.x, bm = blockIdx.y;
  const int wr = w >> 2, wc = w & 3;  // 2M x 4N wave grid; per-wave 64x64
  f32x4 acc[4][4] = {};

  for (int kt = 0; kt < 16; ++kt) {
#pragma unroll
    for (int i = 0; i < 2; ++i) {
      int c = i * 512 + tid;
      int r = c >> 3, scc = (c & 7) ^ (r & 7);
      async_load16(A + (size_t)(bm * 128 + r) * 1024 + kt * 64 + scc * 8,
                   &As[(i * 8 + w) * 512]);
    }
#pragma unroll
    for (int i = 0; i < 4; ++i) {
      int c = i * 512 + tid;
      int r = c >> 3, scc = (c & 7) ^ (r & 7);
      async_load16(Bt + (size_t)(bx * 256 + r) * 1024 + kt * 64 + scc * 8,
                   &Bs[(i * 8 + w) * 512]);
    }
    __syncthreads();
#pragma unroll
    for (int ks = 0; ks < 2; ++ks) {
      short8 af[4], bf[4];
#pragma unroll
      for (int m = 0; m < 4; ++m) {
        int row = wr * 64 + m * 16 + lo;
        int ch = (ks * 4 + hi) ^ (row & 7);
        af[m] = *(const short8*)(&As[row * 64 + ch * 8]);
      }
#pragma unroll
      for (int n = 0; n < 4; ++n) {
        int row = wc * 64 + n * 16 + lo;
        int ch = (ks * 4 + hi) ^ (row & 7);
        bf[n] = *(const short8*)(&Bs[row * 64 + ch * 8]);
      }
#pragma unroll
      for (int m = 0; m < 4; ++m)
#pragma unroll
        for (int n = 0; n < 4; ++n)
          acc[m][n] = __builtin_amdgcn_mfma_f32_16x16x32_bf16(af[m], bf[n], acc[m][n], 0, 0, 0);
    }
    __syncthreads();
  }
  const int colb = bx * 256 + wc * 64 + lo;
#pragma unroll
  for (int m = 0; m < 4; ++m) {
    int row0 = bm * 128 + wr * 64 + m * 16 + hi * 4;
#pragma unroll
    for (int n = 0; n < 4; ++n) {
      int col = colb + n * 16;
      int r3 = col >> 10;
      const float* bp = (r3 == 0) ? bq : ((r3 == 1) ? bk : bv);
      float bs = bp[col & 1023];
      if (r3 == 2) {
        // V region: write directly transposed into Vt[B*H][64][SEQ]
        int vdim = col - 2048;
        int hh = vdim >> 6, dd = vdim & 63;
        int bb = row0 >> 11, ss = row0 & 2047;
        short4v t;
#pragma unroll
        for (int j = 0; j < 4; ++j) t[j] = f2bf(acc[m][n][j] + bs);
        *(short4v*)&VtOut[((size_t)(bb * 16 + hh) * 64 + dd) * SEQ + ss] = t;
      } else {
#pragma unroll
        for (int j = 0; j < 4; ++j)
          Cout[(size_t)(row0 + j) * LDQK + col] = f2bf(acc[m][n][j] + bs);
      }
    }
  }
}

// C[M,N] = A[M,K] @ Bt[N,K]^T + bias + resid(bf16), bf16 out. 128x64 tile,
// 4 waves, dbuf, counted-vmcnt async pipeline (2 tiles in flight, vmcnt(6)
// mid-loop, raw barriers, stage(t+2) after second barrier).
__global__ void __launch_bounds__(256, 2) gemm_n64(
    const short* __restrict__ A, const short* __restrict__ Bt,
    const float* __restrict__ b0, const short* __restrict__ resid,
    short* __restrict__ Cout, int M, int N, int K) {
  __shared__ __align__(16) short As[2][128 * 64];
  __shared__ __align__(16) short Bs[2][64 * 64];
  const int w = threadIdx.x >> 6, lane = threadIdx.x & 63;
  const int hi = lane >> 4, lo = lane & 15;
  const int bm = blockIdx.y, bn = blockIdx.x;
  const int wr = w >> 1, wc = w & 1;
  f32x4 acc[4][2] = {};
  const int nkt = K >> 6;

  auto stage = [&](int kt, int buf) {
#pragma unroll
    for (int j = 0; j < 4; ++j) {
      int c = (j * 4 + w) * 64 + lane;
      int r = c >> 3;
      int scc = (c & 7) ^ (r & 7);
      async_load16(A + (size_t)(bm * 128 + r) * K + kt * 64 + scc * 8,
                   &As[buf][(j * 4 + w) * 512]);
    }
#pragma unroll
    for (int j = 0; j < 2; ++j) {
      int c = j * 256 + w * 64 + lane;
      int r = c >> 3;
      int scc = (c & 7) ^ (r & 7);
      async_load16(Bt + (size_t)(bn * 64 + r) * K + kt * 64 + scc * 8,
                   &Bs[buf][(j * 256 + w * 64) * 8]);
    }
  };

  stage(0, 0);
  stage(1, 1);  // 12 loads in flight (2 tiles)

  for (int kt = 0; kt < nkt; ++kt) {
    const int buf = kt & 1;
    if (kt + 1 < nkt) asm volatile("s_waitcnt vmcnt(6)" ::: "memory");
    else              asm volatile("s_waitcnt vmcnt(0)" ::: "memory");
    __builtin_amdgcn_s_barrier();  // tile kt visible to all waves
#pragma unroll
    for (int ks = 0; ks < 2; ++ks) {
      short8 af[4], bf[2];
#pragma unroll
      for (int m = 0; m < 4; ++m) {
        int row = wr * 64 + m * 16 + lo;
        int ch = (ks * 4 + hi) ^ (row & 7);
        af[m] = *(const short8*)(&As[buf][row * 64 + ch * 8]);
      }
#pragma unroll
      for (int n = 0; n < 2; ++n) {
        int row = wc * 32 + n * 16 + lo;
        int ch = (ks * 4 + hi) ^ (row & 7);
        bf[n] = *(const short8*)(&Bs[buf][row * 64 + ch * 8]);
      }
#pragma unroll
      for (int m = 0; m < 4; ++m)
#pragma unroll
        for (int n = 0; n < 2; ++n)
          acc[m][n] = __builtin_amdgcn_mfma_f32_16x16x32_bf16(af[m], bf[n], acc[m][n], 0, 0, 0);
    }
    __builtin_amdgcn_s_barrier();  // all waves done reading buf
    if (kt + 2 < nkt) stage(kt + 2, buf);  // overwrite buf for tile kt+2
  }
  const int colb = bn * 64 + wc * 32 + lo;
#pragma unroll
  for (int m = 0; m < 4; ++m) {
    int row0 = bm * 128 + wr * 64 + m * 16 + hi * 4;
#pragma unroll
    for (int n = 0; n < 2; ++n) {
      int col = colb + n * 16;
      float bs = b0[col];
#pragma unroll
      for (int j = 0; j < 4; ++j) {
        size_t idx = (size_t)(row0 + j) * N + col;
        Cout[idx] = f2bf(acc[m][n][j] + bs + bf2f(resid[idx]));
      }
    }
  }
}

// 8-wave wide-block GEMM (FF1). Counted-vmcnt async pipeline, 4 loads
// per stage -> vmcnt(4) mid-loop, raw barriers, stage(t+2) after reads done.
template <int EPI, bool RESID>
__global__ void __launch_bounds__(512, 2) gemm_w8d(
    const short* __restrict__ A, const short* __restrict__ Bt,
    const float* __restrict__ b0, const short* __restrict__ resid,
    short* __restrict__ Cout, int M, int N, int K) {
  __shared__ __align__(16) short As[2][128 * 64];
  __shared__ __align__(16) short Bs[2][128 * 64];
  const int tid = threadIdx.x;
  const int w = tid >> 6, lane = tid & 63;
  const int hi = lane >> 4, lo = lane & 15;
  const int bx = blockIdx.x, bm = blockIdx.y;
  const int wr = w >> 2, wc = w & 3;
  f32x4 acc[4][2] = {};
  const int nkt = K >> 6;

  auto stage = [&](int kt, int buf) {
#pragma unroll
    for (int i = 0; i < 2; ++i) {
      int c = i * 512 + tid;
      int r = c >> 3, scc = (c & 7) ^ (r & 7);
      async_load16(A + (size_t)(bm * 128 + r) * K + kt * 64 + scc * 8,
                   &As[buf][(i * 8 + w) * 512]);
    }
#pragma unroll
    for (int i = 0; i < 2; ++i) {
      int c = i * 512 + tid;
      int r = c >> 3, scc = (c & 7) ^ (r & 7);
      async_load16(Bt + (size_t)(bx * 128 + r) * K + kt * 64 + scc * 8,
                   &Bs[buf][(i * 8 + w) * 512]);
    }
  };

  stage(0, 0);
  stage(1, 1);  // 8 loads in flight (2 tiles)

  for (int kt = 0; kt < nkt; ++kt) {
    const int buf = kt & 1;
    if (kt + 1 < nkt) asm volatile("s_waitcnt vmcnt(4)" ::: "memory");
    else              asm volatile("s_waitcnt vmcnt(0)" ::: "memory");
    __builtin_amdgcn_s_barrier();
#pragma unroll
    for (int ks = 0; ks < 2; ++ks) {
      short8 af[4], bf[2];
#pragma unroll
      for (int m = 0; m < 4; ++m) {
        int row = wr * 64 + m * 16 + lo;
        int ch = (ks * 4 + hi) ^ (row & 7);
        af[m] = *(const short8*)(&As[buf][row * 64 + ch * 8]);
      }
#pragma unroll
      for (int n = 0; n < 2; ++n) {
        int row = wc * 32 + n * 16 + lo;
        int ch = (ks * 4 + hi) ^ (row & 7);
        bf[n] = *(const short8*)(&Bs[buf][row * 64 + ch * 8]);
      }
#pragma unroll
      for (int m = 0; m < 4; ++m)
#pragma unroll
        for (int n = 0; n < 2; ++n)
          acc[m][n] = __builtin_amdgcn_mfma_f32_16x16x32_bf16(af[m], bf[n], acc[m][n], 0, 0, 0);
    }
    __builtin_amdgcn_s_barrier();
    if (kt + 2 < nkt) stage(kt + 2, buf);
  }
  const int colb = bx * 128 + wc * 32 + lo;
#pragma unroll
  for (int m = 0; m < 4; ++m) {
    int row0 = bm * 128 + wr * 64 + m * 16 + hi * 4;
#pragma unroll
    for (int n = 0; n < 2; ++n) {
      int col = colb + n * 16;
      float bs = b0[col];
#pragma unroll
      for (int j = 0; j < 4; ++j) {
        size_t idx = (size_t)(row0 + j) * N + col;
        float v = acc[m][n][j] + bs;
        if (EPI == 1) v = 0.5f * v * (1.f + erff(v * 0.70710678f));
        if (RESID) v += bf2f(resid[idx]);
        Cout[idx] = f2bf(v);
      }
    }
  }
}

// Flash attention. 64 q-rows/block (4 waves x 16 rows), KVBLK=64,
// dbuf K/V one-tile-ahead prefetch, 40KB LDS, grid 1024. No-max softmax,
// XOR-swizzled K/V reads, swapped QK^T, wave-private swizzled P,
// XCD-chunked swizzle, setprio around MFMA clusters.
// R23: Q pre-scaled by C=0.125*log2(e) at load (kills 16 muls/tile);
// exp2 forced to bare v_exp_f32 via inline asm.
__global__ void __launch_bounds__(256, 2) attn_kernel(
    const short* __restrict__ Qb, const short* __restrict__ Kb,
    const short* __restrict__ Vt, short* __restrict__ ctx) {
  const int w = threadIdx.x >> 6, lane = threadIdx.x & 63;
  const int hi = lane >> 4, lo = lane & 15;
  const int tid = threadIdx.x;
  const int L = blockIdx.x;
  const int W = (L & 7) * 128 + (L >> 3);
  const int qt = W & 31, bh = W >> 5;
  const int b = bh >> 4, h = bh & 15;
  const int qbase = qt * 64 + w * 16;
  const float C = 0.18033688f;  // 0.125 * log2(e)

  __shared__ __align__(16) short Ks[2][64 * 64];  // 16KB
  __shared__ __align__(16) short Vs[2][64 * 64];  // 16KB
  __shared__ __align__(16) short P[4][16 * 64];   // 8KB (wave-private)

  const short* qp = Qb + (size_t)(b * SEQ + qbase + lo) * LDQK + h * 64;
  short8 bq[2];
#pragma unroll
  for (int c = 0; c < 2; ++c) {
    short8 t = *(const short8*)(qp + c * 32 + hi * 8);
#pragma unroll
    for (int j = 0; j < 8; ++j) t[j] = f2bf(bf2f(t[j]) * C);  // pre-scale Q
    bq[c] = t;
  }

  const short* kb = Kb + (size_t)(b * SEQ) * LDQK + h * 64;
  const short* vb = Vt + (size_t)bh * 64 * SEQ;

  auto stage = [&](int kt, int buf) {
    const short* kg = kb + (size_t)(kt * 64) * LDQK;
#pragma unroll
    for (int i = 0; i < 2; ++i) {
      int c = i * 256 + tid;
      int r = c >> 3, scc = (c & 7) ^ (r & 7);
      async_load16(kg + (size_t)r * LDQK + scc * 8,
                   &Ks[buf][(i * 256 + w * 64) * 8]);
    }
    const short* vg = vb + kt * 64;
#pragma unroll
    for (int i = 0; i < 2; ++i) {
      int c = i * 256 + tid;
      int r = c >> 3, sc2 = (c & 7) ^ (r & 7);
      async_load16(vg + (size_t)r * SEQ + sc2 * 8,
                   &Vs[buf][(i * 256 + w * 64) * 8]);
    }
  };

  stage(0, 0);
  __syncthreads();

  f32x4 o[4] = {};
  float lacc = 0.f;
  const int x7 = lo & 7;

  for (int kt = 0; kt < SEQ / 64; ++kt) {
    const int buf = kt & 1;
    if (kt + 1 < SEQ / 64) stage(kt + 1, buf ^ 1);

    f32x4 s[4] = {};
    __builtin_amdgcn_s_setprio(1);
#pragma unroll
    for (int g = 0; g < 4; ++g) {
      const short* kr = &Ks[buf][(g * 16 + lo) * 64];
      short8 ka0 = *(const short8*)(kr + ((hi) ^ x7) * 8);
      short8 ka1 = *(const short8*)(kr + ((4 + hi) ^ x7) * 8);
      s[g] = __builtin_amdgcn_mfma_f32_16x16x32_bf16(ka0, bq[0], s[g], 0, 0, 0);
      s[g] = __builtin_amdgcn_mfma_f32_16x16x32_bf16(ka1, bq[1], s[g], 0, 0, 0);
    }
    __builtin_amdgcn_s_setprio(0);
    short8 vv[2][4];
#pragma unroll
    for (int ks = 0; ks < 2; ++ks)
#pragma unroll
      for (int a = 0; a < 4; ++a)
        vv[ks][a] = *(const short8*)(&Vs[buf][(a * 16 + lo) * 64 + (((ks * 4 + hi) ^ x7) * 8)]);

    float rsg[4];
    short* pbase = &P[w][0];
#pragma unroll
    for (int g = 0; g < 4; ++g) {
      float p0 = fexp2(s[g][0]);
      float p1 = fexp2(s[g][1]);
      float p2 = fexp2(s[g][2]);
      float p3 = fexp2(s[g][3]);
      rsg[g] = (p0 + p1) + (p2 + p3);
      unsigned w0, w1;
      asm("v_cvt_pk_bf16_f32 %0, %1, %2" : "=v"(w0) : "v"(p0), "v"(p1));
      asm("v_cvt_pk_bf16_f32 %0, %1, %2" : "=v"(w1) : "v"(p2), "v"(p3));
      union { unsigned uu[2]; short4v s4; } cv;
      cv.uu[0] = w0; cv.uu[1] = w1;
      int pc = (2 * g + (hi >> 1)) ^ x7;
      *(short4v*)(pbase + lo * 64 + pc * 8 + (hi & 1) * 4) = cv.s4;
    }
    __builtin_amdgcn_s_setprio(1);
#pragma unroll
    for (int ks = 0; ks < 2; ++ks) {
      int pc = (ks * 4 + hi) ^ x7;
      short8 pa = *(const short8*)(pbase + lo * 64 + pc * 8);
#pragma unroll
      for (int a = 0; a < 4; ++a)
        o[a] = __builtin_amdgcn_mfma_f32_16x16x32_bf16(pa, vv[ks][a], o[a], 0, 0, 0);
    }
    __builtin_amdgcn_s_setprio(0);
    lacc += (rsg[0] + rsg[1]) + (rsg[2] + rsg[3]);
    __syncthreads();
  }
  lacc += __shfl_xor(lacc, 16);
  lacc += __shfl_xor(lacc, 32);
#pragma unroll
  for (int j = 0; j < 4; ++j) {
    float lj = __shfl(lacc, hi * 4 + j);
    float inv = 1.f / lj;
    int row = qbase + hi * 4 + j;
#pragma unroll
    for (int a = 0; a < 4; ++a)
      ctx[(size_t)(b * SEQ + row) * DM + h * 64 + a * 16 + lo] = f2bf(o[a][j] * inv);
  }
}

// out = LN(in)*g + beta, in is bf16 (already residual-summed).
// Writes f32 outf and/or bf16 outb (nullable).
__global__ void __launch_bounds__(256) ln_bf16(
    const short* __restrict__ in, const float* __restrict__ g,
    const float* __restrict__ beta, float* __restrict__ outf,
    short* __restrict__ outb) {
  const int row = blockIdx.x;
  const int t = threadIdx.x;
  const size_t base = (size_t)row * DM;
  short4v iv = ((const short4v*)(in + base))[t];
  f32x4 v;
#pragma unroll
  for (int j = 0; j < 4; ++j) v[j] = bf2f(iv[j]);
  float s = v[0] + v[1] + v[2] + v[3];
  float s2 = v[0] * v[0] + v[1] * v[1] + v[2] * v[2] + v[3] * v[3];
#pragma unroll
  for (int off = 1; off < 64; off <<= 1) {
    s += __shfl_xor(s, off);
    s2 += __shfl_xor(s2, off);
  }
  __shared__ float rs[4], rs2[4];
  if ((t & 63) == 0) { rs[t >> 6] = s; rs2[t >> 6] = s2; }
  __syncthreads();
  s = rs[0] + rs[1] + rs[2] + rs[3];
  s2 = rs2[0] + rs2[1] + rs2[2] + rs2[3];
  float mu = s * (1.f / DM);
  float var = s2 * (1.f / DM) - mu * mu;
  float rstd = rsqrtf(var + 1e-5f);
  f32x4 gv = ((const f32x4*)g)[t];
  f32x4 bv = ((const f32x4*)beta)[t];
  f32x4 ov;
#pragma unroll
  for (int j = 0; j < 4; ++j) ov[j] = (v[j] - mu) * rstd * gv[j] + bv[j];
  if (outf) ((f32x4*)(outf + base))[t] = ov;
  if (outb) {
    short4v sb;
#pragma unroll
    for (int j = 0; j < 4; ++j) sb[j] = f2bf(ov[j]);
    ((short4v*)(outb + base))[t] = sb;
  }
}

extern "C" void kernel_launch(void* const* d_in, const int* in_sizes, int n_in,
                              void* d_out, int out_size, void* d_ws, size_t ws_size,
                              hipStream_t stream) {
  (void)in_sizes; (void)n_in; (void)out_size; (void)ws_size;
  const float* x   = (const float*)d_in[0];
  const float* Wq  = (const float*)d_in[1];
  const float* bq  = (const float*)d_in[2];
  const float* Wk  = (const float*)d_in[3];
  const float* bk  = (const float*)d_in[4];
  const float* Wv  = (const float*)d_in[5];
  const float* bv  = (const float*)d_in[6];
  const float* Wo  = (const float*)d_in[7];
  const float* bo  = (const float*)d_in[8];
  const float* g1  = (const float*)d_in[9];
  const float* b1  = (const float*)d_in[10];
  const float* Wf1 = (const float*)d_in[11];
  const float* bf1 = (const float*)d_in[12];
  const float* Wf2 = (const float*)d_in[13];
  const float* bf2 = (const float*)d_in[14];
  const float* g2  = (const float*)d_in[15];
  const float* b2  = (const float*)d_in[16];

  char* ws = (char*)d_ws;
  const size_t MB = 1u << 20;
  short* Wqkv = (short*)(ws + 0 * MB);    // [3072][1024] bf16, 6 MB
  short* Wto  = (short*)(ws + 6 * MB);    // 2 MB
  short* Wtf1 = (short*)(ws + 8 * MB);    // 4 MB
  short* Wtf2 = (short*)(ws + 12 * MB);   // 4 MB
  short* xb   = (short*)(ws + 16 * MB);   // 8 MB
  short* QKV  = (short*)(ws + 24 * MB);   // [4096][3072] bf16, 24 MB (V third unused)
  short* Vt   = (short*)(ws + 48 * MB);   // 8 MB (written by QKV gemm epilogue)
  short* ctxb = (short*)(ws + 56 * MB);   // 8 MB
  short* aout = (short*)(ws + 64 * MB);   // bf16 (x + ctx@Wo + bo), 8 MB
  short* x1b  = (short*)(ws + 72 * MB);   // bf16 LN1 output, 8 MB
  short* hb   = QKV;                       // QKV dead after attention
  short* ffo  = (short*)(ws + 48 * MB);   // bf16 (x1 + ffn), over Vt (dead)

  prep_all<<<dim3(64, 64, 7), dim3(32, 8), 0, stream>>>(
      Wq, Wk, Wv, Wo, Wf1, Wf2, x, Wqkv, Wto, Wtf1, Wtf2, xb);

  gemm_qkv8<<<dim3(12, 32), 512, 0, stream>>>(xb, Wqkv, bq, bk, bv, QKV, Vt);

  attn_kernel<<<dim3(1024), 256, 0, stream>>>(QKV, QKV + 1024, Vt, ctxb);

  // aout = x + ctx@Wo + bo (residual fused)
  gemm_n64<<<dim3(16, 32), 256, 0, stream>>>(ctxb, Wto, bo, xb, aout, NTOK, 1024, 1024);
  ln_bf16<<<4096, 256, 0, stream>>>(aout, g1, b1, nullptr, x1b);
  // FF1: 8-wave wide-block async pipeline
  gemm_w8d<1, false><<<dim3(16, 32), 512, 0, stream>>>(
      x1b, Wtf1, bf1, nullptr, hb, NTOK, 2048, 1024);
  // ffo = x1 + h@Wf2 + bf2 (residual fused)
  gemm_n64<<<dim3(16, 32), 256, 0, stream>>>(hb, Wtf2, bf2, x1b, ffo, NTOK, 1024, 2048);
  ln_bf16<<<4096, 256, 0, stream>>>(ffo, g2, b2, (float*)d_out, nullptr);
}

// Round 24
// 184.306 us; speedup vs baseline: 1.1300x; 1.0291x over previous
//
#include <hip/hip_runtime.h>

#define SEQ 2048
#define NTOK 4096
#define DM 1024
#define LDQK 3072

typedef __attribute__((ext_vector_type(4))) float f32x4;
typedef __attribute__((ext_vector_type(8))) short short8;
typedef __attribute__((ext_vector_type(4))) short short4v;

__device__ __forceinline__ short f2bf(float f) {
  union { float f; unsigned u; } x; x.f = f;
  unsigned r = x.u + 0x7fffu + ((x.u >> 16) & 1u);
  return (short)(r >> 16);
}

__device__ __forceinline__ float bf2f(short s) {
  union { unsigned u; float f; } x;
  x.u = ((unsigned)(unsigned short)s) << 16;
  return x.f;
}

__device__ __forceinline__ float fexp2(float x) {
  float r;
  asm("v_exp_f32 %0, %1" : "=v"(r) : "v"(x));
  return r;
}

__device__ __forceinline__ float frcp(float x) {
  float r;
  asm("v_rcp_f32 %0, %1" : "=v"(r) : "v"(x));
  return r;
}

// tanh-approx GELU: x*sigmoid(2*sqrt(2/pi)*(x+0.044715x^3)); bare HW ops.
// max |err| vs exact erf-GELU ~3e-4 (safe under bf16 rounding already applied).
__device__ __forceinline__ float gelu_fast(float v) {
  float t = fexp2(-2.3022077f * (v + 0.044715f * v * v * v));
  return v * frcp(1.f + t);
}

__device__ __forceinline__ void async_load16(const void* g, void* l) {
  __builtin_amdgcn_global_load_lds(
      (const __attribute__((address_space(1))) void*)g,
      (__attribute__((address_space(3))) void*)l, 16, 0, 0);
}

// All prep in one launch. z=0..3: 1024x1024 W transposes; z=4: Wf1; z=5: Wf2;
// z=6: x f32->bf16 cast. Block (32,8).
__global__ void __launch_bounds__(256) prep_all(
    const float* __restrict__ Wq, const float* __restrict__ Wk,
    const float* __restrict__ Wv, const float* __restrict__ Wo,
    const float* __restrict__ Wf1, const float* __restrict__ Wf2,
    const float* __restrict__ x,
    short* __restrict__ Wqkv, short* __restrict__ Wto,
    short* __restrict__ Wtf1, short* __restrict__ Wtf2,
    short* __restrict__ xb) {
  const int z = blockIdx.z;
  const int tx = threadIdx.x, ty = threadIdx.y;
  if (z == 6) {
    int blk = blockIdx.y * 64 + blockIdx.x;
    int i = blk * 256 + ty * 32 + tx;
    f32x4 v = ((const f32x4*)x)[i];
    short4v o;
#pragma unroll
    for (int j = 0; j < 4; ++j) o[j] = f2bf(v[j]);
    ((short4v*)xb)[i] = o;
    return;
  }
  const float* in;
  short* out;
  int K, N;
  switch (z) {
    case 0: in = Wq;  out = Wqkv;               K = 1024; N = 1024; break;
    case 1: in = Wk;  out = Wqkv + 1024 * 1024; K = 1024; N = 1024; break;
    case 2: in = Wv;  out = Wqkv + 2048 * 1024; K = 1024; N = 1024; break;
    case 3: in = Wo;  out = Wto;                K = 1024; N = 1024; break;
    case 4: in = Wf1; out = Wtf1;               K = 1024; N = 2048; break;
    default: in = Wf2; out = Wtf2;              K = 2048; N = 1024; break;
  }
  if (blockIdx.x * 32 >= N || blockIdx.y * 32 >= K) return;
  __shared__ float t[32][33];
  const int n = blockIdx.x * 32 + tx;
#pragma unroll
  for (int i = 0; i < 4; ++i) {
    int k = blockIdx.y * 32 + ty + i * 8;
    t[ty + i * 8][tx] = in[(size_t)k * N + n];
  }
  __syncthreads();
  const int k2 = blockIdx.y * 32 + tx;
#pragma unroll
  for (int i = 0; i < 4; ++i) {
    int n2 = blockIdx.x * 32 + ty + i * 8;
    out[(size_t)n2 * K + k2] = f2bf(t[tx][ty + i * 8]);
  }
}

// QKV fused GEMM, 8 waves / 512 threads, block output 128x256.
// grid (12, 32). V region written directly transposed into Vt[B*H][64][SEQ].
__global__ void __launch_bounds__(512, 2) gemm_qkv8(
    const short* __restrict__ A, const short* __restrict__ Bt,
    const float* __restrict__ bq, const float* __restrict__ bk,
    const float* __restrict__ bv, short* __restrict__ Cout,
    short* __restrict__ VtOut) {
  __shared__ __align__(16) short As[128 * 64];   // 16KB
  __shared__ __align__(16) short Bs[256 * 64];   // 32KB
  const int tid = threadIdx.x;
  const int w = tid >> 6, lane = tid & 63;
  const int hi = lane >> 4, lo = lane & 15;
  const int bx = blockIdx.x, bm = blockIdx.y;
  const int wr = w >> 2, wc = w & 3;  // 2M x 4N wave grid; per-wave 64x64
  f32x4 acc[4][4] = {};

  for (int kt = 0; kt < 16; ++kt) {
#pragma unroll
    for (int i = 0; i < 2; ++i) {
      int c = i * 512 + tid;
      int r = c >> 3, scc = (c & 7) ^ (r & 7);
      async_load16(A + (size_t)(bm * 128 + r) * 1024 + kt * 64 + scc * 8,
                   &As[(i * 8 + w) * 512]);
    }
#pragma unroll
    for (int i = 0; i < 4; ++i) {
      int c = i * 512 + tid;
      int r = c >> 3, scc = (c & 7) ^ (r & 7);
      async_load16(Bt + (size_t)(bx * 256 + r) * 1024 + kt * 64 + scc * 8,
                   &Bs[(i * 8 + w) * 512]);
    }
    __syncthreads();
#pragma unroll
    for (int ks = 0; ks < 2; ++ks) {
      short8 af[4], bf[4];
#pragma unroll
      for (int m = 0; m < 4; ++m) {
        int row = wr * 64 + m * 16 + lo;
        int ch = (ks * 4 + hi) ^ (row & 7);
        af[m] = *(const short8*)(&As[row * 64 + ch * 8]);
      }
#pragma unroll
      for (int n = 0; n < 4; ++n) {
        int row = wc * 64 + n * 16 + lo;
        int ch = (ks * 4 + hi) ^ (row & 7);
        bf[n] = *(const short8*)(&Bs[row * 64 + ch * 8]);
      }
#pragma unroll
      for (int m = 0; m < 4; ++m)
#pragma unroll
        for (int n = 0; n < 4; ++n)
          acc[m][n] = __builtin_amdgcn_mfma_f32_16x16x32_bf16(af[m], bf[n], acc[m][n], 0, 0, 0);
    }
    __syncthreads();
  }
  const int colb = bx * 256 + wc * 64 + lo;
#pragma unroll
  for (int m = 0; m < 4; ++m) {
    int row0 = bm * 128 + wr * 64 + m * 16 + hi * 4;
#pragma unroll
    for (int n = 0; n < 4; ++n) {
      int col = colb + n * 16;
      int r3 = col >> 10;
      const float* bp = (r3 == 0) ? bq : ((r3 == 1) ? bk : bv);
      float bs = bp[col & 1023];
      if (r3 == 2) {
        // V region: write directly transposed into Vt[B*H][64][SEQ]
        int vdim = col - 2048;
        int hh = vdim >> 6, dd = vdim & 63;
        int bb = row0 >> 11, ss = row0 & 2047;
        short4v t;
#pragma unroll
        for (int j = 0; j < 4; ++j) t[j] = f2bf(acc[m][n][j] + bs);
        *(short4v*)&VtOut[((size_t)(bb * 16 + hh) * 64 + dd) * SEQ + ss] = t;
      } else {
#pragma unroll
        for (int j = 0; j < 4; ++j)
          Cout[(size_t)(row0 + j) * LDQK + col] = f2bf(acc[m][n][j] + bs);
      }
    }
  }
}

// C[M,N] = A[M,K] @ Bt[N,K]^T + bias + resid(bf16), bf16 out. 128x64 tile,
// 4 waves, dbuf, counted-vmcnt async pipeline (2 tiles in flight, vmcnt(6)
// mid-loop, raw barriers, stage(t+2) after second barrier).
__global__ void __launch_bounds__(256, 2) gemm_n64(
    const short* __restrict__ A, const short* __restrict__ Bt,
    const float* __restrict__ b0, const short* __restrict__ resid,
    short* __restrict__ Cout, int M, int N, int K) {
  __shared__ __align__(16) short As[2][128 * 64];
  __shared__ __align__(16) short Bs[2][64 * 64];
  const int w = threadIdx.x >> 6, lane = threadIdx.x & 63;
  const int hi = lane >> 4, lo = lane & 15;
  const int bm = blockIdx.y, bn = blockIdx.x;
  const int wr = w >> 1, wc = w & 1;
  f32x4 acc[4][2] = {};
  const int nkt = K >> 6;

  auto stage = [&](int kt, int buf) {
#pragma unroll
    for (int j = 0; j < 4; ++j) {
      int c = (j * 4 + w) * 64 + lane;
      int r = c >> 3;
      int scc = (c & 7) ^ (r & 7);
      async_load16(A + (size_t)(bm * 128 + r) * K + kt * 64 + scc * 8,
                   &As[buf][(j * 4 + w) * 512]);
    }
#pragma unroll
    for (int j = 0; j < 2; ++j) {
      int c = j * 256 + w * 64 + lane;
      int r = c >> 3;
      int scc = (c & 7) ^ (r & 7);
      async_load16(Bt + (size_t)(bn * 64 + r) * K + kt * 64 + scc * 8,
                   &Bs[buf][(j * 256 + w * 64) * 8]);
    }
  };

  stage(0, 0);
  stage(1, 1);  // 12 loads in flight (2 tiles)

  for (int kt = 0; kt < nkt; ++kt) {
    const int buf = kt & 1;
    if (kt + 1 < nkt) asm volatile("s_waitcnt vmcnt(6)" ::: "memory");
    else              asm volatile("s_waitcnt vmcnt(0)" ::: "memory");
    __builtin_amdgcn_s_barrier();  // tile kt visible to all waves
#pragma unroll
    for (int ks = 0; ks < 2; ++ks) {
      short8 af[4], bf[2];
#pragma unroll
      for (int m = 0; m < 4; ++m) {
        int row = wr * 64 + m * 16 + lo;
        int ch = (ks * 4 + hi) ^ (row & 7);
        af[m] = *(const short8*)(&As[buf][row * 64 + ch * 8]);
      }
#pragma unroll
      for (int n = 0; n < 2; ++n) {
        int row = wc * 32 + n * 16 + lo;
        int ch = (ks * 4 + hi) ^ (row & 7);
        bf[n] = *(const short8*)(&Bs[buf][row * 64 + ch * 8]);
      }
#pragma unroll
      for (int m = 0; m < 4; ++m)
#pragma unroll
        for (int n = 0; n < 2; ++n)
          acc[m][n] = __builtin_amdgcn_mfma_f32_16x16x32_bf16(af[m], bf[n], acc[m][n], 0, 0, 0);
    }
    __builtin_amdgcn_s_barrier();  // all waves done reading buf
    if (kt + 2 < nkt) stage(kt + 2, buf);  // overwrite buf for tile kt+2
  }
  const int colb = bn * 64 + wc * 32 + lo;
#pragma unroll
  for (int m = 0; m < 4; ++m) {
    int row0 = bm * 128 + wr * 64 + m * 16 + hi * 4;
#pragma unroll
    for (int n = 0; n < 2; ++n) {
      int col = colb + n * 16;
      float bs = b0[col];
#pragma unroll
      for (int j = 0; j < 4; ++j) {
        size_t idx = (size_t)(row0 + j) * N + col;
        Cout[idx] = f2bf(acc[m][n][j] + bs + bf2f(resid[idx]));
      }
    }
  }
}

// 8-wave wide-block GEMM (FF1). Counted-vmcnt async pipeline, 4 loads
// per stage -> vmcnt(4) mid-loop, raw barriers, stage(t+2) after reads done.
// R24: GELU epilogue uses tanh-approx with bare v_exp/v_rcp (no OCML erff).
template <int EPI, bool RESID>
__global__ void __launch_bounds__(512, 2) gemm_w8d(
    const short* __restrict__ A, const short* __restrict__ Bt,
    const float* __restrict__ b0, const short* __restrict__ resid,
    short* __restrict__ Cout, int M, int N, int K) {
  __shared__ __align__(16) short As[2][128 * 64];
  __shared__ __align__(16) short Bs[2][128 * 64];
  const int tid = threadIdx.x;
  const int w = tid >> 6, lane = tid & 63;
  const int hi = lane >> 4, lo = lane & 15;
  const int bx = blockIdx.x, bm = blockIdx.y;
  const int wr = w >> 2, wc = w & 3;
  f32x4 acc[4][2] = {};
  const int nkt = K >> 6;

  auto stage = [&](int kt, int buf) {
#pragma unroll
    for (int i = 0; i < 2; ++i) {
      int c = i * 512 + tid;
      int r = c >> 3, scc = (c & 7) ^ (r & 7);
      async_load16(A + (size_t)(bm * 128 + r) * K + kt * 64 + scc * 8,
                   &As[buf][(i * 8 + w) * 512]);
    }
#pragma unroll
    for (int i = 0; i < 2; ++i) {
      int c = i * 512 + tid;
      int r = c >> 3, scc = (c & 7) ^ (r & 7);
      async_load16(Bt + (size_t)(bx * 128 + r) * K + kt * 64 + scc * 8,
                   &Bs[buf][(i * 8 + w) * 512]);
    }
  };

  stage(0, 0);
  stage(1, 1);  // 8 loads in flight (2 tiles)

  for (int kt = 0; kt < nkt; ++kt) {
    const int buf = kt & 1;
    if (kt + 1 < nkt) asm volatile("s_waitcnt vmcnt(4)" ::: "memory");
    else              asm volatile("s_waitcnt vmcnt(0)" ::: "memory");
    __builtin_amdgcn_s_barrier();
#pragma unroll
    for (int ks = 0; ks < 2; ++ks) {
      short8 af[4], bf[2];
#pragma unroll
      for (int m = 0; m < 4; ++m) {
        int row = wr * 64 + m * 16 + lo;
        int ch = (ks * 4 + hi) ^ (row & 7);
        af[m] = *(const short8*)(&As[buf][row * 64 + ch * 8]);
      }
#pragma unroll
      for (int n = 0; n < 2; ++n) {
        int row = wc * 32 + n * 16 + lo;
        int ch = (ks * 4 + hi) ^ (row & 7);
        bf[n] = *(const short8*)(&Bs[buf][row * 64 + ch * 8]);
      }
#pragma unroll
      for (int m = 0; m < 4; ++m)
#pragma unroll
        for (int n = 0; n < 2; ++n)
          acc[m][n] = __builtin_amdgcn_mfma_f32_16x16x32_bf16(af[m], bf[n], acc[m][n], 0, 0, 0);
    }
    __builtin_amdgcn_s_barrier();
    if (kt + 2 < nkt) stage(kt + 2, buf);
  }
  const int colb = bx * 128 + wc * 32 + lo;
#pragma unroll
  for (int m = 0; m < 4; ++m) {
    int row0 = bm * 128 + wr * 64 + m * 16 + hi * 4;
#pragma unroll
    for (int n = 0; n < 2; ++n) {
      int col = colb + n * 16;
      float bs = b0[col];
#pragma unroll
      for (int j = 0; j < 4; ++j) {
        size_t idx = (size_t)(row0 + j) * N + col;
        float v = acc[m][n][j] + bs;
        if (EPI == 1) v = gelu_fast(v);
        if (RESID) v += bf2f(resid[idx]);
        Cout[idx] = f2bf(v);
      }
    }
  }
}

// Flash attention. 64 q-rows/block (4 waves x 16 rows), KVBLK=64,
// dbuf K/V one-tile-ahead prefetch, 40KB LDS, grid 1024. No-max softmax
// (Q pre-scaled by C, bare v_exp_f32), XOR-swizzled K/V reads, swapped QK^T,
// wave-private swizzled P, XCD-chunked swizzle, setprio around MFMA.
__global__ void __launch_bounds__(256, 2) attn_kernel(
    const short* __restrict__ Qb, const short* __restrict__ Kb,
    const short* __restrict__ Vt, short* __restrict__ ctx) {
  const int w = threadIdx.x >> 6, lane = threadIdx.x & 63;
  const int hi = lane >> 4, lo = lane & 15;
  const int tid = threadIdx.x;
  const int L = blockIdx.x;
  const int W = (L & 7) * 128 + (L >> 3);
  const int qt = W & 31, bh = W >> 5;
  const int b = bh >> 4, h = bh & 15;
  const int qbase = qt * 64 + w * 16;
  const float C = 0.18033688f;  // 0.125 * log2(e)

  __shared__ __align__(16) short Ks[2][64 * 64];  // 16KB
  __shared__ __align__(16) short Vs[2][64 * 64];  // 16KB
  __shared__ __align__(16) short P[4][16 * 64];   // 8KB (wave-private)

  const short* qp = Qb + (size_t)(b * SEQ + qbase + lo) * LDQK + h * 64;
  short8 bq[2];
#pragma unroll
  for (int c = 0; c < 2; ++c) {
    short8 t = *(const short8*)(qp + c * 32 + hi * 8);
#pragma unroll
    for (int j = 0; j < 8; ++j) t[j] = f2bf(bf2f(t[j]) * C);  // pre-scale Q
    bq[c] = t;
  }

  const short* kb = Kb + (size_t)(b * SEQ) * LDQK + h * 64;
  const short* vb = Vt + (size_t)bh * 64 * SEQ;

  auto stage = [&](int kt, int buf) {
    const short* kg = kb + (size_t)(kt * 64) * LDQK;
#pragma unroll
    for (int i = 0; i < 2; ++i) {
      int c = i * 256 + tid;
      int r = c >> 3, scc = (c & 7) ^ (r & 7);
      async_load16(kg + (size_t)r * LDQK + scc * 8,
                   &Ks[buf][(i * 256 + w * 64) * 8]);
    }
    const short* vg = vb + kt * 64;
#pragma unroll
    for (int i = 0; i < 2; ++i) {
      int c = i * 256 + tid;
      int r = c >> 3, sc2 = (c & 7) ^ (r & 7);
      async_load16(vg + (size_t)r * SEQ + sc2 * 8,
                   &Vs[buf][(i * 256 + w * 64) * 8]);
    }
  };

  stage(0, 0);
  __syncthreads();

  f32x4 o[4] = {};
  float lacc = 0.f;
  const int x7 = lo & 7;

  for (int kt = 0; kt < SEQ / 64; ++kt) {
    const int buf = kt & 1;
    if (kt + 1 < SEQ / 64) stage(kt + 1, buf ^ 1);

    f32x4 s[4] = {};
    __builtin_amdgcn_s_setprio(1);
#pragma unroll
    for (int g = 0; g < 4; ++g) {
      const short* kr = &Ks[buf][(g * 16 + lo) * 64];
      short8 ka0 = *(const short8*)(kr + ((hi) ^ x7) * 8);
      short8 ka1 = *(const short8*)(kr + ((4 + hi) ^ x7) * 8);
      s[g] = __builtin_amdgcn_mfma_f32_16x16x32_bf16(ka0, bq[0], s[g], 0, 0, 0);
      s[g] = __builtin_amdgcn_mfma_f32_16x16x32_bf16(ka1, bq[1], s[g], 0, 0, 0);
    }
    __builtin_amdgcn_s_setprio(0);
    short8 vv[2][4];
#pragma unroll
    for (int ks = 0; ks < 2; ++ks)
#pragma unroll
      for (int a = 0; a < 4; ++a)
        vv[ks][a] = *(const short8*)(&Vs[buf][(a * 16 + lo) * 64 + (((ks * 4 + hi) ^ x7) * 8)]);

    float rsg[4];
    short* pbase = &P[w][0];
#pragma unroll
    for (int g = 0; g < 4; ++g) {
      float p0 = fexp2(s[g][0]);
      float p1 = fexp2(s[g][1]);
      float p2 = fexp2(s[g][2]);
      float p3 = fexp2(s[g][3]);
      rsg[g] = (p0 + p1) + (p2 + p3);
      unsigned w0, w1;
      asm("v_cvt_pk_bf16_f32 %0, %1, %2" : "=v"(w0) : "v"(p0), "v"(p1));
      asm("v_cvt_pk_bf16_f32 %0, %1, %2" : "=v"(w1) : "v"(p2), "v"(p3));
      union { unsigned uu[2]; short4v s4; } cv;
      cv.uu[0] = w0; cv.uu[1] = w1;
      int pc = (2 * g + (hi >> 1)) ^ x7;
      *(short4v*)(pbase + lo * 64 + pc * 8 + (hi & 1) * 4) = cv.s4;
    }
    __builtin_amdgcn_s_setprio(1);
#pragma unroll
    for (int ks = 0; ks < 2; ++ks) {
      int pc = (ks * 4 + hi) ^ x7;
      short8 pa = *(const short8*)(pbase + lo * 64 + pc * 8);
#pragma unroll
      for (int a = 0; a < 4; ++a)
        o[a] = __builtin_amdgcn_mfma_f32_16x16x32_bf16(pa, vv[ks][a], o[a], 0, 0, 0);
    }
    __builtin_amdgcn_s_setprio(0);
    lacc += (rsg[0] + rsg[1]) + (rsg[2] + rsg[3]);
    __syncthreads();
  }
  lacc += __shfl_xor(lacc, 16);
  lacc += __shfl_xor(lacc, 32);
#pragma unroll
  for (int j = 0; j < 4; ++j) {
    float lj = __shfl(lacc, hi * 4 + j);
    float inv = 1.f / lj;
    int row = qbase + hi * 4 + j;
#pragma unroll
    for (int a = 0; a < 4; ++a)
      ctx[(size_t)(b * SEQ + row) * DM + h * 64 + a * 16 + lo] = f2bf(o[a][j] * inv);
  }
}

// out = LN(in)*g + beta, in is bf16 (already residual-summed).
// Writes f32 outf and/or bf16 outb (nullable).
__global__ void __launch_bounds__(256) ln_bf16(
    const short* __restrict__ in, const float* __restrict__ g,
    const float* __restrict__ beta, float* __restrict__ outf,
    short* __restrict__ outb) {
  const int row = blockIdx.x;
  const int t = threadIdx.x;
  const size_t base = (size_t)row * DM;
  short4v iv = ((const short4v*)(in + base))[t];
  f32x4 v;
#pragma unroll
  for (int j = 0; j < 4; ++j) v[j] = bf2f(iv[j]);
  float s = v[0] + v[1] + v[2] + v[3];
  float s2 = v[0] * v[0] + v[1] * v[1] + v[2] * v[2] + v[3] * v[3];
#pragma unroll
  for (int off = 1; off < 64; off <<= 1) {
    s += __shfl_xor(s, off);
    s2 += __shfl_xor(s2, off);
  }
  __shared__ float rs[4], rs2[4];
  if ((t & 63) == 0) { rs[t >> 6] = s; rs2[t >> 6] = s2; }
  __syncthreads();
  s = rs[0] + rs[1] + rs[2] + rs[3];
  s2 = rs2[0] + rs2[1] + rs2[2] + rs2[3];
  float mu = s * (1.f / DM);
  float var = s2 * (1.f / DM) - mu * mu;
  float rstd = rsqrtf(var + 1e-5f);
  f32x4 gv = ((const f32x4*)g)[t];
  f32x4 bv = ((const f32x4*)beta)[t];
  f32x4 ov;
#pragma unroll
  for (int j = 0; j < 4; ++j) ov[j] = (v[j] - mu) * rstd * gv[j] + bv[j];
  if (outf) ((f32x4*)(outf + base))[t] = ov;
  if (outb) {
    short4v sb;
#pragma unroll
    for (int j = 0; j < 4; ++j) sb[j] = f2bf(ov[j]);
    ((short4v*)(outb + base))[t] = sb;
  }
}

extern "C" void kernel_launch(void* const* d_in, const int* in_sizes, int n_in,
                              void* d_out, int out_size, void* d_ws, size_t ws_size,
                              hipStream_t stream) {
  (void)in_sizes; (void)n_in; (void)out_size; (void)ws_size;
  const float* x   = (const float*)d_in[0];
  const float* Wq  = (const float*)d_in[1];
  const float* bq  = (const float*)d_in[2];
  const float* Wk  = (const float*)d_in[3];
  const float* bk  = (const float*)d_in[4];
  const float* Wv  = (const float*)d_in[5];
  const float* bv  = (const float*)d_in[6];
  const float* Wo  = (const float*)d_in[7];
  const float* bo  = (const float*)d_in[8];
  const float* g1  = (const float*)d_in[9];
  const float* b1  = (const float*)d_in[10];
  const float* Wf1 = (const float*)d_in[11];
  const float* bf1 = (const float*)d_in[12];
  const float* Wf2 = (const float*)d_in[13];
  const float* bf2 = (const float*)d_in[14];
  const float* g2  = (const float*)d_in[15];
  const float* b2  = (const float*)d_in[16];

  char* ws = (char*)d_ws;
  const size_t MB = 1u << 20;
  short* Wqkv = (short*)(ws + 0 * MB);    // [3072][1024] bf16, 6 MB
  short* Wto  = (short*)(ws + 6 * MB);    // 2 MB
  short* Wtf1 = (short*)(ws + 8 * MB);    // 4 MB
  short* Wtf2 = (short*)(ws + 12 * MB);   // 4 MB
  short* xb   = (short*)(ws + 16 * MB);   // 8 MB
  short* QKV  = (short*)(ws + 24 * MB);   // [4096][3072] bf16, 24 MB (V third unused)
  short* Vt   = (short*)(ws + 48 * MB);   // 8 MB (written by QKV gemm epilogue)
  short* ctxb = (short*)(ws + 56 * MB);   // 8 MB
  short* aout = (short*)(ws + 64 * MB);   // bf16 (x + ctx@Wo + bo), 8 MB
  short* x1b  = (short*)(ws + 72 * MB);   // bf16 LN1 output, 8 MB
  short* hb   = QKV;                       // QKV dead after attention
  short* ffo  = (short*)(ws + 48 * MB);   // bf16 (x1 + ffn), over Vt (dead)

  prep_all<<<dim3(64, 64, 7), dim3(32, 8), 0, stream>>>(
      Wq, Wk, Wv, Wo, Wf1, Wf2, x, Wqkv, Wto, Wtf1, Wtf2, xb);

  gemm_qkv8<<<dim3(12, 32), 512, 0, stream>>>(xb, Wqkv, bq, bk, bv, QKV, Vt);

  attn_kernel<<<dim3(1024), 256, 0, stream>>>(QKV, QKV + 1024, Vt, ctxb);

  // aout = x + ctx@Wo + bo (residual fused)
  gemm_n64<<<dim3(16, 32), 256, 0, stream>>>(ctxb, Wto, bo, xb, aout, NTOK, 1024, 1024);
  ln_bf16<<<4096, 256, 0, stream>>>(aout, g1, b1, nullptr, x1b);
  // FF1: 8-wave wide-block async pipeline, fast GELU
  gemm_w8d<1, false><<<dim3(16, 32), 512, 0, stream>>>(
      x1b, Wtf1, bf1, nullptr, hb, NTOK, 2048, 1024);
  // ffo = x1 + h@Wf2 + bf2 (residual fused)
  gemm_n64<<<dim3(16, 32), 256, 0, stream>>>(hb, Wtf2, bf2, x1b, ffo, NTOK, 1024, 2048);
  ln_bf16<<<4096, 256, 0, stream>>>(ffo, g2, b2, (float*)d_out, nullptr);
}

// Round 25
// 184.177 us; speedup vs baseline: 1.1308x; 1.0007x over previous
//
#include <hip/hip_runtime.h>

#define SEQ 2048
#define NTOK 4096
#define DM 1024
#define LDQK 3072

typedef __attribute__((ext_vector_type(4))) float f32x4;
typedef __attribute__((ext_vector_type(8))) short short8;
typedef __attribute__((ext_vector_type(4))) short short4v;

__device__ __forceinline__ short f2bf(float f) {
  union { float f; unsigned u; } x; x.f = f;
  unsigned r = x.u + 0x7fffu + ((x.u >> 16) & 1u);
  return (short)(r >> 16);
}

__device__ __forceinline__ float bf2f(short s) {
  union { unsigned u; float f; } x;
  x.u = ((unsigned)(unsigned short)s) << 16;
  return x.f;
}

__device__ __forceinline__ float fexp2(float x) {
  float r;
  asm("v_exp_f32 %0, %1" : "=v"(r) : "v"(x));
  return r;
}

__device__ __forceinline__ float frcp(float x) {
  float r;
  asm("v_rcp_f32 %0, %1" : "=v"(r) : "v"(x));
  return r;
}

// tanh-approx GELU: x*sigmoid(2*sqrt(2/pi)*(x+0.044715x^3)); bare HW ops.
__device__ __forceinline__ float gelu_fast(float v) {
  float t = fexp2(-2.3022077f * (v + 0.044715f * v * v * v));
  return v * frcp(1.f + t);
}

__device__ __forceinline__ void async_load16(const void* g, void* l) {
  __builtin_amdgcn_global_load_lds(
      (const __attribute__((address_space(1))) void*)g,
      (__attribute__((address_space(3))) void*)l, 16, 0, 0);
}

// All prep in one launch. z=0..3: 1024x1024 W transposes; z=4: Wf1; z=5: Wf2;
// z=6: x f32->bf16 cast. Block (32,8).
__global__ void __launch_bounds__(256) prep_all(
    const float* __restrict__ Wq, const float* __restrict__ Wk,
    const float* __restrict__ Wv, const float* __restrict__ Wo,
    const float* __restrict__ Wf1, const float* __restrict__ Wf2,
    const float* __restrict__ x,
    short* __restrict__ Wqkv, short* __restrict__ Wto,
    short* __restrict__ Wtf1, short* __restrict__ Wtf2,
    short* __restrict__ xb) {
  const int z = blockIdx.z;
  const int tx = threadIdx.x, ty = threadIdx.y;
  if (z == 6) {
    int blk = blockIdx.y * 64 + blockIdx.x;
    int i = blk * 256 + ty * 32 + tx;
    f32x4 v = ((const f32x4*)x)[i];
    short4v o;
#pragma unroll
    for (int j = 0; j < 4; ++j) o[j] = f2bf(v[j]);
    ((short4v*)xb)[i] = o;
    return;
  }
  const float* in;
  short* out;
  int K, N;
  switch (z) {
    case 0: in = Wq;  out = Wqkv;               K = 1024; N = 1024; break;
    case 1: in = Wk;  out = Wqkv + 1024 * 1024; K = 1024; N = 1024; break;
    case 2: in = Wv;  out = Wqkv + 2048 * 1024; K = 1024; N = 1024; break;
    case 3: in = Wo;  out = Wto;                K = 1024; N = 1024; break;
    case 4: in = Wf1; out = Wtf1;               K = 1024; N = 2048; break;
    default: in = Wf2; out = Wtf2;              K = 2048; N = 1024; break;
  }
  if (blockIdx.x * 32 >= N || blockIdx.y * 32 >= K) return;
  __shared__ float t[32][33];
  const int n = blockIdx.x * 32 + tx;
#pragma unroll
  for (int i = 0; i < 4; ++i) {
    int k = blockIdx.y * 32 + ty + i * 8;
    t[ty + i * 8][tx] = in[(size_t)k * N + n];
  }
  __syncthreads();
  const int k2 = blockIdx.y * 32 + tx;
#pragma unroll
  for (int i = 0; i < 4; ++i) {
    int n2 = blockIdx.x * 32 + ty + i * 8;
    out[(size_t)n2 * K + k2] = f2bf(t[tx][ty + i * 8]);
  }
}

// QKV fused GEMM, 8 waves / 512 threads, block output 128x256.
// grid (12, 32). V region written directly transposed into Vt[B*H][64][SEQ].
__global__ void __launch_bounds__(512, 2) gemm_qkv8(
    const short* __restrict__ A, const short* __restrict__ Bt,
    const float* __restrict__ bq, const float* __restrict__ bk,
    const float* __restrict__ bv, short* __restrict__ Cout,
    short* __restrict__ VtOut) {
  __shared__ __align__(16) short As[128 * 64];   // 16KB
  __shared__ __align__(16) short Bs[256 * 64];   // 32KB
  const int tid = threadIdx.x;
  const int w = tid >> 6, lane = tid & 63;
  const int hi = lane >> 4, lo = lane & 15;
  const int bx = blockIdx.x, bm = blockIdx.y;
  const int wr = w >> 2, wc = w & 3;  // 2M x 4N wave grid; per-wave 64x64
  f32x4 acc[4][4] = {};

  for (int kt = 0; kt < 16; ++kt) {
#pragma unroll
    for (int i = 0; i < 2; ++i) {
      int c = i * 512 + tid;
      int r = c >> 3, scc = (c & 7) ^ (r & 7);
      async_load16(A + (size_t)(bm * 128 + r) * 1024 + kt * 64 + scc * 8,
                   &As[(i * 8 + w) * 512]);
    }
#pragma unroll
    for (int i = 0; i < 4; ++i) {
      int c = i * 512 + tid;
      int r = c >> 3, scc = (c & 7) ^ (r & 7);
      async_load16(Bt + (size_t)(bx * 256 + r) * 1024 + kt * 64 + scc * 8,
                   &Bs[(i * 8 + w) * 512]);
    }
    __syncthreads();
#pragma unroll
    for (int ks = 0; ks < 2; ++ks) {
      short8 af[4], bf[4];
#pragma unroll
      for (int m = 0; m < 4; ++m) {
        int row = wr * 64 + m * 16 + lo;
        int ch = (ks * 4 + hi) ^ (row & 7);
        af[m] = *(const short8*)(&As[row * 64 + ch * 8]);
      }
#pragma unroll
      for (int n = 0; n < 4; ++n) {
        int row = wc * 64 + n * 16 + lo;
        int ch = (ks * 4 + hi) ^ (row & 7);
        bf[n] = *(const short8*)(&Bs[row * 64 + ch * 8]);
      }
#pragma unroll
      for (int m = 0; m < 4; ++m)
#pragma unroll
        for (int n = 0; n < 4; ++n)
          acc[m][n] = __builtin_amdgcn_mfma_f32_16x16x32_bf16(af[m], bf[n], acc[m][n], 0, 0, 0);
    }
    __syncthreads();
  }
  const int colb = bx * 256 + wc * 64 + lo;
#pragma unroll
  for (int m = 0; m < 4; ++m) {
    int row0 = bm * 128 + wr * 64 + m * 16 + hi * 4;
#pragma unroll
    for (int n = 0; n < 4; ++n) {
      int col = colb + n * 16;
      int r3 = col >> 10;
      const float* bp = (r3 == 0) ? bq : ((r3 == 1) ? bk : bv);
      float bs = bp[col & 1023];
      if (r3 == 2) {
        // V region: write directly transposed into Vt[B*H][64][SEQ]
        int vdim = col - 2048;
        int hh = vdim >> 6, dd = vdim & 63;
        int bb = row0 >> 11, ss = row0 & 2047;
        short4v t;
#pragma unroll
        for (int j = 0; j < 4; ++j) t[j] = f2bf(acc[m][n][j] + bs);
        *(short4v*)&VtOut[((size_t)(bb * 16 + hh) * 64 + dd) * SEQ + ss] = t;
      } else {
#pragma unroll
        for (int j = 0; j < 4; ++j)
          Cout[(size_t)(row0 + j) * LDQK + col] = f2bf(acc[m][n][j] + bs);
      }
    }
  }
}

// C[M,N] = A[M,K] @ Bt[N,K]^T + bias + resid(bf16), bf16 out. 128x64 tile,
// 4 waves, dbuf, counted-vmcnt async pipeline (2 tiles in flight, vmcnt(6)
// mid-loop, raw barriers, stage(t+2) after second barrier).
__global__ void __launch_bounds__(256, 2) gemm_n64(
    const short* __restrict__ A, const short* __restrict__ Bt,
    const float* __restrict__ b0, const short* __restrict__ resid,
    short* __restrict__ Cout, int M, int N, int K) {
  __shared__ __align__(16) short As[2][128 * 64];
  __shared__ __align__(16) short Bs[2][64 * 64];
  const int w = threadIdx.x >> 6, lane = threadIdx.x & 63;
  const int hi = lane >> 4, lo = lane & 15;
  const int bm = blockIdx.y, bn = blockIdx.x;
  const int wr = w >> 1, wc = w & 1;
  f32x4 acc[4][2] = {};
  const int nkt = K >> 6;

  auto stage = [&](int kt, int buf) {
#pragma unroll
    for (int j = 0; j < 4; ++j) {
      int c = (j * 4 + w) * 64 + lane;
      int r = c >> 3;
      int scc = (c & 7) ^ (r & 7);
      async_load16(A + (size_t)(bm * 128 + r) * K + kt * 64 + scc * 8,
                   &As[buf][(j * 4 + w) * 512]);
    }
#pragma unroll
    for (int j = 0; j < 2; ++j) {
      int c = j * 256 + w * 64 + lane;
      int r = c >> 3;
      int scc = (c & 7) ^ (r & 7);
      async_load16(Bt + (size_t)(bn * 64 + r) * K + kt * 64 + scc * 8,
                   &Bs[buf][(j * 256 + w * 64) * 8]);
    }
  };

  stage(0, 0);
  stage(1, 1);  // 12 loads in flight (2 tiles)

  for (int kt = 0; kt < nkt; ++kt) {
    const int buf = kt & 1;
    if (kt + 1 < nkt) asm volatile("s_waitcnt vmcnt(6)" ::: "memory");
    else              asm volatile("s_waitcnt vmcnt(0)" ::: "memory");
    __builtin_amdgcn_s_barrier();  // tile kt visible to all waves
#pragma unroll
    for (int ks = 0; ks < 2; ++ks) {
      short8 af[4], bf[2];
#pragma unroll
      for (int m = 0; m < 4; ++m) {
        int row = wr * 64 + m * 16 + lo;
        int ch = (ks * 4 + hi) ^ (row & 7);
        af[m] = *(const short8*)(&As[buf][row * 64 + ch * 8]);
      }
#pragma unroll
      for (int n = 0; n < 2; ++n) {
        int row = wc * 32 + n * 16 + lo;
        int ch = (ks * 4 + hi) ^ (row & 7);
        bf[n] = *(const short8*)(&Bs[buf][row * 64 + ch * 8]);
      }
#pragma unroll
      for (int m = 0; m < 4; ++m)
#pragma unroll
        for (int n = 0; n < 2; ++n)
          acc[m][n] = __builtin_amdgcn_mfma_f32_16x16x32_bf16(af[m], bf[n], acc[m][n], 0, 0, 0);
    }
    __builtin_amdgcn_s_barrier();  // all waves done reading buf
    if (kt + 2 < nkt) stage(kt + 2, buf);  // overwrite buf for tile kt+2
  }
  const int colb = bn * 64 + wc * 32 + lo;
#pragma unroll
  for (int m = 0; m < 4; ++m) {
    int row0 = bm * 128 + wr * 64 + m * 16 + hi * 4;
#pragma unroll
    for (int n = 0; n < 2; ++n) {
      int col = colb + n * 16;
      float bs = b0[col];
#pragma unroll
      for (int j = 0; j < 4; ++j) {
        size_t idx = (size_t)(row0 + j) * N + col;
        Cout[idx] = f2bf(acc[m][n][j] + bs + bf2f(resid[idx]));
      }
    }
  }
}

// 8-wave wide-block GEMM (FF1). Counted-vmcnt async pipeline, 4 loads
// per stage -> vmcnt(4) mid-loop, raw barriers, stage(t+2) after reads done.
// GELU epilogue uses tanh-approx with bare v_exp/v_rcp (no OCML erff).
template <int EPI, bool RESID>
__global__ void __launch_bounds__(512, 2) gemm_w8d(
    const short* __restrict__ A, const short* __restrict__ Bt,
    const float* __restrict__ b0, const short* __restrict__ resid,
    short* __restrict__ Cout, int M, int N, int K) {
  __shared__ __align__(16) short As[2][128 * 64];
  __shared__ __align__(16) short Bs[2][128 * 64];
  const int tid = threadIdx.x;
  const int w = tid >> 6, lane = tid & 63;
  const int hi = lane >> 4, lo = lane & 15;
  const int bx = blockIdx.x, bm = blockIdx.y;
  const int wr = w >> 2, wc = w & 3;
  f32x4 acc[4][2] = {};
  const int nkt = K >> 6;

  auto stage = [&](int kt, int buf) {
#pragma unroll
    for (int i = 0; i < 2; ++i) {
      int c = i * 512 + tid;
      int r = c >> 3, scc = (c & 7) ^ (r & 7);
      async_load16(A + (size_t)(bm * 128 + r) * K + kt * 64 + scc * 8,
                   &As[buf][(i * 8 + w) * 512]);
    }
#pragma unroll
    for (int i = 0; i < 2; ++i) {
      int c = i * 512 + tid;
      int r = c >> 3, scc = (c & 7) ^ (r & 7);
      async_load16(Bt + (size_t)(bx * 128 + r) * K + kt * 64 + scc * 8,
                   &Bs[buf][(i * 8 + w) * 512]);
    }
  };

  stage(0, 0);
  stage(1, 1);  // 8 loads in flight (2 tiles)

  for (int kt = 0; kt < nkt; ++kt) {
    const int buf = kt & 1;
    if (kt + 1 < nkt) asm volatile("s_waitcnt vmcnt(4)" ::: "memory");
    else              asm volatile("s_waitcnt vmcnt(0)" ::: "memory");
    __builtin_amdgcn_s_barrier();
#pragma unroll
    for (int ks = 0; ks < 2; ++ks) {
      short8 af[4], bf[2];
#pragma unroll
      for (int m = 0; m < 4; ++m) {
        int row = wr * 64 + m * 16 + lo;
        int ch = (ks * 4 + hi) ^ (row & 7);
        af[m] = *(const short8*)(&As[buf][row * 64 + ch * 8]);
      }
#pragma unroll
      for (int n = 0; n < 2; ++n) {
        int row = wc * 32 + n * 16 + lo;
        int ch = (ks * 4 + hi) ^ (row & 7);
        bf[n] = *(const short8*)(&Bs[buf][row * 64 + ch * 8]);
      }
#pragma unroll
      for (int m = 0; m < 4; ++m)
#pragma unroll
        for (int n = 0; n < 2; ++n)
          acc[m][n] = __builtin_amdgcn_mfma_f32_16x16x32_bf16(af[m], bf[n], acc[m][n], 0, 0, 0);
    }
    __builtin_amdgcn_s_barrier();
    if (kt + 2 < nkt) stage(kt + 2, buf);
  }
  const int colb = bx * 128 + wc * 32 + lo;
#pragma unroll
  for (int m = 0; m < 4; ++m) {
    int row0 = bm * 128 + wr * 64 + m * 16 + hi * 4;
#pragma unroll
    for (int n = 0; n < 2; ++n) {
      int col = colb + n * 16;
      float bs = b0[col];
#pragma unroll
      for (int j = 0; j < 4; ++j) {
        size_t idx = (size_t)(row0 + j) * N + col;
        float v = acc[m][n][j] + bs;
        if (EPI == 1) v = gelu_fast(v);
        if (RESID) v += bf2f(resid[idx]);
        Cout[idx] = f2bf(v);
      }
    }
  }
}

// Flash attention. 64 q-rows/block (4 waves x 16 rows), KVBLK=64, grid 1024.
// R25: counted-vmcnt async pipeline (2 K/V tiles in flight, vmcnt(4)
// mid-loop, raw barriers, stage(kt+2) after compute) — the R22-proven GEMM
// sync structure. No-max softmax (Q pre-scaled by C, bare v_exp_f32),
// XOR-swizzled K/V reads, swapped QK^T, wave-private swizzled P,
// XCD-chunked swizzle, setprio around MFMA.
__global__ void __launch_bounds__(256, 2) attn_kernel(
    const short* __restrict__ Qb, const short* __restrict__ Kb,
    const short* __restrict__ Vt, short* __restrict__ ctx) {
  const int w = threadIdx.x >> 6, lane = threadIdx.x & 63;
  const int hi = lane >> 4, lo = lane & 15;
  const int tid = threadIdx.x;
  const int L = blockIdx.x;
  const int W = (L & 7) * 128 + (L >> 3);
  const int qt = W & 31, bh = W >> 5;
  const int b = bh >> 4, h = bh & 15;
  const int qbase = qt * 64 + w * 16;
  const float C = 0.18033688f;  // 0.125 * log2(e)

  __shared__ __align__(16) short Ks[2][64 * 64];  // 16KB
  __shared__ __align__(16) short Vs[2][64 * 64];  // 16KB
  __shared__ __align__(16) short P[4][16 * 64];   // 8KB (wave-private)

  const short* qp = Qb + (size_t)(b * SEQ + qbase + lo) * LDQK + h * 64;
  short8 bq[2];
#pragma unroll
  for (int c = 0; c < 2; ++c) {
    short8 t = *(const short8*)(qp + c * 32 + hi * 8);
#pragma unroll
    for (int j = 0; j < 8; ++j) t[j] = f2bf(bf2f(t[j]) * C);  // pre-scale Q
    bq[c] = t;
  }

  const short* kb = Kb + (size_t)(b * SEQ) * LDQK + h * 64;
  const short* vb = Vt + (size_t)bh * 64 * SEQ;

  // 4 loads per thread per stage (2 K + 2 V)
  auto stage = [&](int kt, int buf) {
    const short* kg = kb + (size_t)(kt * 64) * LDQK;
#pragma unroll
    for (int i = 0; i < 2; ++i) {
      int c = i * 256 + tid;
      int r = c >> 3, scc = (c & 7) ^ (r & 7);
      async_load16(kg + (size_t)r * LDQK + scc * 8,
                   &Ks[buf][(i * 256 + w * 64) * 8]);
    }
    const short* vg = vb + kt * 64;
#pragma unroll
    for (int i = 0; i < 2; ++i) {
      int c = i * 256 + tid;
      int r = c >> 3, sc2 = (c & 7) ^ (r & 7);
      async_load16(vg + (size_t)r * SEQ + sc2 * 8,
                   &Vs[buf][(i * 256 + w * 64) * 8]);
    }
  };

  stage(0, 0);
  stage(1, 1);  // 8 loads in flight (2 tiles)

  f32x4 o[4] = {};
  float lacc = 0.f;
  const int x7 = lo & 7;
  const int NT = SEQ / 64;

  for (int kt = 0; kt < NT; ++kt) {
    const int buf = kt & 1;
    // wait only for tile kt's 4 loads; tile kt+1's stay in flight
    if (kt + 1 < NT) asm volatile("s_waitcnt vmcnt(4)" ::: "memory");
    else             asm volatile("s_waitcnt vmcnt(0)" ::: "memory");
    __builtin_amdgcn_s_barrier();  // all waves' parts of tile kt landed

    f32x4 s[4] = {};
    __builtin_amdgcn_s_setprio(1);
#pragma unroll
    for (int g = 0; g < 4; ++g) {
      const short* kr = &Ks[buf][(g * 16 + lo) * 64];
      short8 ka0 = *(const short8*)(kr + ((hi) ^ x7) * 8);
      short8 ka1 = *(const short8*)(kr + ((4 + hi) ^ x7) * 8);
      s[g] = __builtin_amdgcn_mfma_f32_16x16x32_bf16(ka0, bq[0], s[g], 0, 0, 0);
      s[g] = __builtin_amdgcn_mfma_f32_16x16x32_bf16(ka1, bq[1], s[g], 0, 0, 0);
    }
    __builtin_amdgcn_s_setprio(0);
    short8 vv[2][4];
#pragma unroll
    for (int ks = 0; ks < 2; ++ks)
#pragma unroll
      for (int a = 0; a < 4; ++a)
        vv[ks][a] = *(const short8*)(&Vs[buf][(a * 16 + lo) * 64 + (((ks * 4 + hi) ^ x7) * 8)]);

    float rsg[4];
    short* pbase = &P[w][0];
#pragma unroll
    for (int g = 0; g < 4; ++g) {
      float p0 = fexp2(s[g][0]);
      float p1 = fexp2(s[g][1]);
      float p2 = fexp2(s[g][2]);
      float p3 = fexp2(s[g][3]);
      rsg[g] = (p0 + p1) + (p2 + p3);
      unsigned w0, w1;
      asm("v_cvt_pk_bf16_f32 %0, %1, %2" : "=v"(w0) : "v"(p0), "v"(p1));
      asm("v_cvt_pk_bf16_f32 %0, %1, %2" : "=v"(w1) : "v"(p2), "v"(p3));
      union { unsigned uu[2]; short4v s4; } cv;
      cv.uu[0] = w0; cv.uu[1] = w1;
      int pc = (2 * g + (hi >> 1)) ^ x7;
      *(short4v*)(pbase + lo * 64 + pc * 8 + (hi & 1) * 4) = cv.s4;
    }
    __builtin_amdgcn_s_setprio(1);
#pragma unroll
    for (int ks = 0; ks < 2; ++ks) {
      int pc = (ks * 4 + hi) ^ x7;
      short8 pa = *(const short8*)(pbase + lo * 64 + pc * 8);
#pragma unroll
      for (int a = 0; a < 4; ++a)
        o[a] = __builtin_amdgcn_mfma_f32_16x16x32_bf16(pa, vv[ks][a], o[a], 0, 0, 0);
    }
    __builtin_amdgcn_s_setprio(0);
    lacc += (rsg[0] + rsg[1]) + (rsg[2] + rsg[3]);

    __builtin_amdgcn_s_barrier();  // all waves done reading buf
    if (kt + 2 < NT) stage(kt + 2, buf);  // overwrite buf for tile kt+2
  }
  lacc += __shfl_xor(lacc, 16);
  lacc += __shfl_xor(lacc, 32);
#pragma unroll
  for (int j = 0; j < 4; ++j) {
    float lj = __shfl(lacc, hi * 4 + j);
    float inv = 1.f / lj;
    int row = qbase + hi * 4 + j;
#pragma unroll
    for (int a = 0; a < 4; ++a)
      ctx[(size_t)(b * SEQ + row) * DM + h * 64 + a * 16 + lo] = f2bf(o[a][j] * inv);
  }
}

// out = LN(in)*g + beta, in is bf16 (already residual-summed).
// Writes f32 outf and/or bf16 outb (nullable).
__global__ void __launch_bounds__(256) ln_bf16(
    const short* __restrict__ in, const float* __restrict__ g,
    const float* __restrict__ beta, float* __restrict__ outf,
    short* __restrict__ outb) {
  const int row = blockIdx.x;
  const int t = threadIdx.x;
  const size_t base = (size_t)row * DM;
  short4v iv = ((const short4v*)(in + base))[t];
  f32x4 v;
#pragma unroll
  for (int j = 0; j < 4; ++j) v[j] = bf2f(iv[j]);
  float s = v[0] + v[1] + v[2] + v[3];
  float s2 = v[0] * v[0] + v[1] * v[1] + v[2] * v[2] + v[3] * v[3];
#pragma unroll
  for (int off = 1; off < 64; off <<= 1) {
    s += __shfl_xor(s, off);
    s2 += __shfl_xor(s2, off);
  }
  __shared__ float rs[4], rs2[4];
  if ((t & 63) == 0) { rs[t >> 6] = s; rs2[t >> 6] = s2; }
  __syncthreads();
  s = rs[0] + rs[1] + rs[2] + rs[3];
  s2 = rs2[0] + rs2[1] + rs2[2] + rs2[3];
  float mu = s * (1.f / DM);
  float var = s2 * (1.f / DM) - mu * mu;
  float rstd = rsqrtf(var + 1e-5f);
  f32x4 gv = ((const f32x4*)g)[t];
  f32x4 bv = ((const f32x4*)beta)[t];
  f32x4 ov;
#pragma unroll
  for (int j = 0; j < 4; ++j) ov[j] = (v[j] - mu) * rstd * gv[j] + bv[j];
  if (outf) ((f32x4*)(outf + base))[t] = ov;
  if (outb) {
    short4v sb;
#pragma unroll
    for (int j = 0; j < 4; ++j) sb[j] = f2bf(ov[j]);
    ((short4v*)(outb + base))[t] = sb;
  }
}

extern "C" void kernel_launch(void* const* d_in, const int* in_sizes, int n_in,
                              void* d_out, int out_size, void* d_ws, size_t ws_size,
                              hipStream_t stream) {
  (void)in_sizes; (void)n_in; (void)out_size; (void)ws_size;
  const float* x   = (const float*)d_in[0];
  const float* Wq  = (const float*)d_in[1];
  const float* bq  = (const float*)d_in[2];
  const float* Wk  = (const float*)d_in[3];
  const float* bk  = (const float*)d_in[4];
  const float* Wv  = (const float*)d_in[5];
  const float* bv  = (const float*)d_in[6];
  const float* Wo  = (const float*)d_in[7];
  const float* bo  = (const float*)d_in[8];
  const float* g1  = (const float*)d_in[9];
  const float* b1  = (const float*)d_in[10];
  const float* Wf1 = (const float*)d_in[11];
  const float* bf1 = (const float*)d_in[12];
  const float* Wf2 = (const float*)d_in[13];
  const float* bf2 = (const float*)d_in[14];
  const float* g2  = (const float*)d_in[15];
  const float* b2  = (const float*)d_in[16];

  char* ws = (char*)d_ws;
  const size_t MB = 1u << 20;
  short* Wqkv = (short*)(ws + 0 * MB);    // [3072][1024] bf16, 6 MB
  short* Wto  = (short*)(ws + 6 * MB);    // 2 MB
  short* Wtf1 = (short*)(ws + 8 * MB);    // 4 MB
  short* Wtf2 = (short*)(ws + 12 * MB);   // 4 MB
  short* xb   = (short*)(ws + 16 * MB);   // 8 MB
  short* QKV  = (short*)(ws + 24 * MB);   // [4096][3072] bf16, 24 MB (V third unused)
  short* Vt   = (short*)(ws + 48 * MB);   // 8 MB (written by QKV gemm epilogue)
  short* ctxb = (short*)(ws + 56 * MB);   // 8 MB
  short* aout = (short*)(ws + 64 * MB);   // bf16 (x + ctx@Wo + bo), 8 MB
  short* x1b  = (short*)(ws + 72 * MB);   // bf16 LN1 output, 8 MB
  short* hb   = QKV;                       // QKV dead after attention
  short* ffo  = (short*)(ws + 48 * MB);   // bf16 (x1 + ffn), over Vt (dead)

  prep_all<<<dim3(64, 64, 7), dim3(32, 8), 0, stream>>>(
      Wq, Wk, Wv, Wo, Wf1, Wf2, x, Wqkv, Wto, Wtf1, Wtf2, xb);

  gemm_qkv8<<<dim3(12, 32), 512, 0, stream>>>(xb, Wqkv, bq, bk, bv, QKV, Vt);

  attn_kernel<<<dim3(1024), 256, 0, stream>>>(QKV, QKV + 1024, Vt, ctxb);

  // aout = x + ctx@Wo + bo (residual fused)
  gemm_n64<<<dim3(16, 32), 256, 0, stream>>>(ctxb, Wto, bo, xb, aout, NTOK, 1024, 1024);
  ln_bf16<<<4096, 256, 0, stream>>>(aout, g1, b1, nullptr, x1b);
  // FF1: 8-wave wide-block async pipeline, fast GELU
  gemm_w8d<1, false><<<dim3(16, 32), 512, 0, stream>>>(
      x1b, Wtf1, bf1, nullptr, hb, NTOK, 2048, 1024);
  // ffo = x1 + h@Wf2 + bf2 (residual fused)
  gemm_n64<<<dim3(16, 32), 256, 0, stream>>>(hb, Wtf2, bf2, x1b, ffo, NTOK, 1024, 2048);
  ln_bf16<<<4096, 256, 0, stream>>>(ffo, g2, b2, (float*)d_out, nullptr);
}